// Round 4
// baseline (208.825 us; speedup 1.0000x reference)
//
#include <hip/hip_runtime.h>
#include <cstdint>

// Shapes (fixed by the problem): B=2, C=64, G=4 -> CG=256, DQK=8, L=64*64=4096
constexpr int Bc  = 2;
constexpr int CGc = 256;
constexpr int Dc  = 8;
constexpr int Lc  = 4096;

typedef __attribute__((ext_vector_type(8))) short short8;
typedef __attribute__((ext_vector_type(4))) float floatx4;

__device__ inline unsigned short f2bf(float f) {
  union { float f; unsigned u; } v; v.f = f;
  unsigned r = v.u + 0x7fffu + ((v.u >> 16) & 1u);
  return (unsigned short)(r >> 16);
}
__device__ inline float bf2f(unsigned short h) {
  return __uint_as_float((unsigned)h << 16);
}

// ---------------------------------------------------------------------------
// Phase -1: zero Mrow(8192) + Ssum(8192) — contiguous 16384 floats.
// ---------------------------------------------------------------------------
__global__ __launch_bounds__(256) void init_stats(float* __restrict__ p) {
  p[blockIdx.x * 256 + threadIdx.x] = 0.f;
}

// ---------------------------------------------------------------------------
// Phase 0: Wcat[cc][k] bf16 = [[Wr, -Wi], [Wi, Wr]] (512x512) for v_gemm.
// ---------------------------------------------------------------------------
__global__ __launch_bounds__(256) void wcat_pack(const float* __restrict__ wv,
                                                 unsigned short* __restrict__ Wcat) {
  const int i  = blockIdx.x * 256 + threadIdx.x;  // 0..262143
  const int cc = i >> 9, k = i & 511;
  const int co = cc >> 8, c = cc & 255, ci = k >> 8, cin = k & 255;
  const float wr = wv[(size_t)c * CGc + cin];
  const float wi = wv[(size_t)(CGc + c) * CGc + cin];
  const float val = co == 0 ? (ci == 0 ? wr : -wi) : (ci == 0 ? wi : wr);
  Wcat[i] = f2bf(val);
}

// ---------------------------------------------------------------------------
// Phase 0b: LDS-transpose x -> Xlk[b][l][cin2] bf16 (cin2 = comp*256+cin).
// ---------------------------------------------------------------------------
__global__ __launch_bounds__(256) void xT_pack(const float* __restrict__ x,
                                               unsigned short* __restrict__ Xlk) {
  __shared__ float xs[64][65];
  const int tid = threadIdx.x;
  const int b   = blockIdx.z;
  const int l0  = blockIdx.x * 64;
  const int c0  = blockIdx.y * 64;
  const int lt  = tid & 63, r4 = tid >> 6;
#pragma unroll
  for (int p = 0; p < 16; ++p) {
    const int row  = p * 4 + r4;
    const int cin2 = c0 + row;
    const int comp = cin2 >> 8, cin = cin2 & 255;
    xs[row][lt] = x[((size_t)(comp * Bc + b) * CGc + cin) * Lc + l0 + lt];
  }
  __syncthreads();
#pragma unroll
  for (int p = 0; p < 16; ++p) {
    const int lr = p * 4 + r4;
    Xlk[((size_t)b * Lc + l0 + lr) * 512 + c0 + lt] = f2bf(xs[lt][lr]);
  }
}

// ---------------------------------------------------------------------------
// Phase 1: complex Q AND K projections in one pass (x read once, fp32).
// ---------------------------------------------------------------------------
__global__ __launch_bounds__(256) void qk_proj(const float* __restrict__ x,
                                               const float* __restrict__ wq,
                                               const float* __restrict__ wk,
                                               float* __restrict__ qout,
                                               float* __restrict__ kout) {
  __shared__ float ws[4 * Dc * CGc];  // 32 KB: wq_r | wq_i | wk_r | wk_i
  const int tid = threadIdx.x;
  const int b   = blockIdx.y;
  for (int i = tid; i < 2 * Dc * CGc; i += 256) {
    ws[i]                 = wq[i];
    ws[2 * Dc * CGc + i]  = wk[i];
  }
  __syncthreads();
  const int d  = tid >> 5;   // 0..7
  const int ml = tid & 31;   // 0..31
  const int m  = blockIdx.x * 32 + ml;
  const float* xr = x + ((size_t)(0 * Bc + b) * CGc) * Lc + m;
  const float* xi = x + ((size_t)(1 * Bc + b) * CGc) * Lc + m;
  const float* wqr = ws + d * CGc;
  const float* wqi = ws + (Dc + d) * CGc;
  const float* wkr = ws + 2 * Dc * CGc + d * CGc;
  const float* wki = ws + 2 * Dc * CGc + (Dc + d) * CGc;
  float qer = 0.f, qei = 0.f, ker = 0.f, kei = 0.f;
#pragma unroll 4
  for (int cin = 0; cin < CGc; ++cin) {
    const float vr = xr[(size_t)cin * Lc];
    const float vi = xi[(size_t)cin * Lc];
    const float a1 = wqr[cin], b1 = wqi[cin];
    qer = fmaf(a1, vr, qer); qer = fmaf(-b1, vi, qer);
    qei = fmaf(a1, vi, qei); qei = fmaf(b1, vr, qei);
    const float a2 = wkr[cin], b2 = wki[cin];
    ker = fmaf(a2, vr, ker); ker = fmaf(-b2, vi, ker);
    kei = fmaf(a2, vi, kei); kei = fmaf(b2, vr, kei);
  }
  float* qp = qout + ((size_t)b * Lc + m) * 16;
  qp[d]     = qer;
  qp[8 + d] = qei;
  float* kp = kout + ((size_t)b * Lc + m) * 16;
  kp[d]     = ker;
  kp[8 + d] = kei;
}

// ---------------------------------------------------------------------------
// Phase 1b: split-bf16 packing for MFMA QK^T.
//   Qcat [r][32] = [bf16hi(q~), bf16lo(q~)]   (q~ = [qr(8), qi(8)])
//   K1hi/K1lo [r][16] for k~1=[kr,-ki];  K2hi/K2lo for k~2=[ki,kr].
// er = q~.k~1 via 2 chained MFMAs (lo dup'd across quads: extra qlo.klo term
// is ~2^-18, harmless). One thread per row r = b*L+m.
// ---------------------------------------------------------------------------
__global__ __launch_bounds__(256) void qk_pack(const float* __restrict__ q,
                                               const float* __restrict__ k,
                                               unsigned short* __restrict__ Qcat,
                                               unsigned short* __restrict__ K1hi,
                                               unsigned short* __restrict__ K1lo,
                                               unsigned short* __restrict__ K2hi,
                                               unsigned short* __restrict__ K2lo) {
  const int r = blockIdx.x * 256 + threadIdx.x;  // 0..8191
  {
    const float* qp = q + (size_t)r * 16;
    unsigned u[16];
#pragma unroll
    for (int t = 0; t < 8; ++t) {
      const float v0 = qp[2 * t], v1 = qp[2 * t + 1];
      const unsigned short h0 = f2bf(v0), h1 = f2bf(v1);
      u[t] = (unsigned)h0 | ((unsigned)h1 << 16);
      const unsigned short l0 = f2bf(v0 - bf2f(h0));
      const unsigned short l1 = f2bf(v1 - bf2f(h1));
      u[8 + t] = (unsigned)l0 | ((unsigned)l1 << 16);
    }
    uint4* dst = (uint4*)(Qcat + (size_t)r * 32);
    dst[0] = make_uint4(u[0], u[1], u[2], u[3]);
    dst[1] = make_uint4(u[4], u[5], u[6], u[7]);
    dst[2] = make_uint4(u[8], u[9], u[10], u[11]);
    dst[3] = make_uint4(u[12], u[13], u[14], u[15]);
  }
  {
    const float* kp = k + (size_t)r * 16;
    float k1[16], k2[16];
#pragma unroll
    for (int d = 0; d < 8; ++d) {
      const float kr = kp[d], ki = kp[8 + d];
      k1[d] = kr;  k1[8 + d] = -ki;
      k2[d] = ki;  k2[8 + d] = kr;
    }
    unsigned uh[8], ul[8];
#pragma unroll
    for (int t = 0; t < 8; ++t) {
      const unsigned short h0 = f2bf(k1[2 * t]), h1 = f2bf(k1[2 * t + 1]);
      uh[t] = (unsigned)h0 | ((unsigned)h1 << 16);
      const unsigned short l0 = f2bf(k1[2 * t] - bf2f(h0));
      const unsigned short l1 = f2bf(k1[2 * t + 1] - bf2f(h1));
      ul[t] = (unsigned)l0 | ((unsigned)l1 << 16);
    }
    uint4* dh = (uint4*)(K1hi + (size_t)r * 16);
    dh[0] = make_uint4(uh[0], uh[1], uh[2], uh[3]);
    dh[1] = make_uint4(uh[4], uh[5], uh[6], uh[7]);
    uint4* dl = (uint4*)(K1lo + (size_t)r * 16);
    dl[0] = make_uint4(ul[0], ul[1], ul[2], ul[3]);
    dl[1] = make_uint4(ul[4], ul[5], ul[6], ul[7]);
#pragma unroll
    for (int t = 0; t < 8; ++t) {
      const unsigned short h0 = f2bf(k2[2 * t]), h1 = f2bf(k2[2 * t + 1]);
      uh[t] = (unsigned)h0 | ((unsigned)h1 << 16);
      const unsigned short l0 = f2bf(k2[2 * t] - bf2f(h0));
      const unsigned short l1 = f2bf(k2[2 * t + 1] - bf2f(h1));
      ul[t] = (unsigned)l0 | ((unsigned)l1 << 16);
    }
    uint4* dh2 = (uint4*)(K2hi + (size_t)r * 16);
    dh2[0] = make_uint4(uh[0], uh[1], uh[2], uh[3]);
    dh2[1] = make_uint4(uh[4], uh[5], uh[6], uh[7]);
    uint4* dl2 = (uint4*)(K2lo + (size_t)r * 16);
    dl2[0] = make_uint4(ul[0], ul[1], ul[2], ul[3]);
    dl2[1] = make_uint4(ul[4], ul[5], ul[6], ul[7]);
  }
}

// ---------------------------------------------------------------------------
// Phase 2: V projection as bf16 MFMA GEMM: v[cc][l] = sum_k Wcat[cc][k]*Xlk[l][k].
// Same swizzled+pipelined structure as before; K=512.
// ---------------------------------------------------------------------------
__global__ __launch_bounds__(256) void v_gemm(const unsigned short* __restrict__ Wcat,
                                              const unsigned short* __restrict__ Xlk,
                                              unsigned short* __restrict__ vbf) {
  __shared__ short As[128 * 64];
  __shared__ short Bs[64 * 64];
  const int tid  = threadIdx.x;
  const int b    = blockIdx.z;
  const int cc0  = blockIdx.x * 128;
  const int l0   = blockIdx.y * 64;
  const int wid  = tid >> 6, lane = tid & 63;
  const int wcc  = (wid >> 1) * 64;
  const int wl   = (wid & 1) * 32;
  const int lrow = lane & 15, quad = lane >> 4;
  floatx4 acc[4][2] = {};
  const unsigned short* wsrc = Wcat + (size_t)cc0 * 512;
  const unsigned short* xsrc = Xlk + ((size_t)b * Lc + l0) * 512;
  int s_off[4], g_off[4];
#pragma unroll
  for (int r = 0; r < 4; ++r) {
    const int idx = r * 256 + tid;
    const int row = idx >> 3, ch = idx & 7;
    s_off[r] = row * 64 + (ch ^ (row & 7)) * 8;
    g_off[r] = row * 512 + ch * 8;
  }
  short8 ar[4], br[2];
#pragma unroll
  for (int r = 0; r < 4; ++r) ar[r] = *(const short8*)(wsrc + g_off[r]);
#pragma unroll
  for (int r = 0; r < 2; ++r) br[r] = *(const short8*)(xsrc + g_off[r]);
  for (int k0 = 0; k0 < 512; k0 += 64) {
    __syncthreads();
#pragma unroll
    for (int r = 0; r < 4; ++r) *(short8*)&As[s_off[r]] = ar[r];
#pragma unroll
    for (int r = 0; r < 2; ++r) *(short8*)&Bs[s_off[r]] = br[r];
    __syncthreads();
    if (k0 + 64 < 512) {
#pragma unroll
      for (int r = 0; r < 4; ++r) ar[r] = *(const short8*)(wsrc + g_off[r] + k0 + 64);
#pragma unroll
      for (int r = 0; r < 2; ++r) br[r] = *(const short8*)(xsrc + g_off[r] + k0 + 64);
    }
#pragma unroll
    for (int kk = 0; kk < 64; kk += 32) {
      const int cb = kk >> 3;  // 0 or 4
      short8 af[4], bf[2];
#pragma unroll
      for (int i = 0; i < 4; ++i)
        af[i] = *(const short8*)&As[(wcc + i * 16 + lrow) * 64 +
                                    ((cb + quad) ^ (lrow & 7)) * 8];
#pragma unroll
      for (int j = 0; j < 2; ++j)
        bf[j] = *(const short8*)&Bs[(wl + j * 16 + lrow) * 64 +
                                    ((cb + quad) ^ (lrow & 7)) * 8];
#pragma unroll
      for (int i = 0; i < 4; ++i)
#pragma unroll
        for (int j = 0; j < 2; ++j)
          acc[i][j] = __builtin_amdgcn_mfma_f32_16x16x32_bf16(af[i], bf[j], acc[i][j], 0, 0, 0);
    }
  }
#pragma unroll
  for (int i = 0; i < 4; ++i) {
    const int ccb = cc0 + wcc + i * 16 + quad * 4;
#pragma unroll
    for (int j = 0; j < 2; ++j) {
      const int l = l0 + wl + j * 16 + lrow;
#pragma unroll
      for (int rg = 0; rg < 4; ++rg)
        vbf[((size_t)b * 512 + ccb + rg) * Lc + l] = f2bf(acc[i][j][rg]);
    }
  }
}

// ---------------------------------------------------------------------------
// Phase 3: row max of E via MFMA QK^T, hi-only (shift needs only approx max:
// error <= E*2^-8 ~ 7 -> exp <= e^7, safe; shift cancels in normalization).
// ---------------------------------------------------------------------------
__global__ __launch_bounds__(256) void e_max(const unsigned short* __restrict__ Qcat,
                                             const unsigned short* __restrict__ K1hi,
                                             const unsigned short* __restrict__ K2hi,
                                             float* __restrict__ Mrow) {
  const int tid  = threadIdx.x;
  const int w    = tid >> 6, lane = tid & 63;
  const int lrow = lane & 15, quad = lane >> 4, qsel = quad & 1;
  const int b    = blockIdx.z;
  const int m16  = blockIdx.x * 64 + w * 16;
  const int lbeg = blockIdx.y * 512;
  const size_t kb = (size_t)b * Lc;
  const short8 afrag = *(const short8*)(Qcat + (kb + m16 + lrow) * 32 + quad * 8);
  float mx[4] = {0.f, 0.f, 0.f, 0.f};
  for (int l0 = lbeg; l0 < lbeg + 512; l0 += 16) {
    const size_t l = kb + l0 + lrow;
    const short8 b1h = *(const short8*)(K1hi + l * 16 + qsel * 8);
    const short8 b2h = *(const short8*)(K2hi + l * 16 + qsel * 8);
    const floatx4 er = __builtin_amdgcn_mfma_f32_16x16x32_bf16(afrag, b1h, (floatx4){0.f, 0.f, 0.f, 0.f}, 0, 0, 0);
    const floatx4 ei = __builtin_amdgcn_mfma_f32_16x16x32_bf16(afrag, b2h, (floatx4){0.f, 0.f, 0.f, 0.f}, 0, 0, 0);
#pragma unroll
    for (int r = 0; r < 4; ++r) {
      float e = er[r] * er[r];
      e = fmaf(ei[r], ei[r], e);
      mx[r] = fmaxf(mx[r], e);
    }
  }
#pragma unroll
  for (int r = 0; r < 4; ++r) {
    float v = mx[r];
#pragma unroll
    for (int off = 1; off < 16; off <<= 1) v = fmaxf(v, __shfl_xor(v, off));
    if (lrow == 0)
      atomicMax((unsigned*)&Mrow[kb + m16 + quad * 4 + r], __float_as_uint(v));
  }
}

// ---------------------------------------------------------------------------
// Phase 4: att[m][l] = bf16(__expf(E-M)) (unnormalized), refined split-bf16 E;
// partial row sums -> atomicAdd(Ssum).
// ---------------------------------------------------------------------------
__global__ __launch_bounds__(256) void e_exp(const unsigned short* __restrict__ Qcat,
                                             const unsigned short* __restrict__ K1hi,
                                             const unsigned short* __restrict__ K1lo,
                                             const unsigned short* __restrict__ K2hi,
                                             const unsigned short* __restrict__ K2lo,
                                             const float* __restrict__ Mrow,
                                             unsigned short* __restrict__ att,
                                             float* __restrict__ Ssum) {
  const int tid  = threadIdx.x;
  const int w    = tid >> 6, lane = tid & 63;
  const int lrow = lane & 15, quad = lane >> 4, qsel = quad & 1;
  const int b    = blockIdx.z;
  const int m16  = blockIdx.x * 64 + w * 16;
  const int lbeg = blockIdx.y * 512;
  const size_t kb = (size_t)b * Lc;
  const short8 afrag = *(const short8*)(Qcat + (kb + m16 + lrow) * 32 + quad * 8);
  float Mv[4], sum[4] = {};
#pragma unroll
  for (int r = 0; r < 4; ++r) Mv[r] = Mrow[kb + m16 + quad * 4 + r];
  for (int l0 = lbeg; l0 < lbeg + 512; l0 += 16) {
    const size_t l = kb + l0 + lrow;
    const short8 b1h = *(const short8*)(K1hi + l * 16 + qsel * 8);
    const short8 b1l = *(const short8*)(K1lo + l * 16 + qsel * 8);
    const short8 b2h = *(const short8*)(K2hi + l * 16 + qsel * 8);
    const short8 b2l = *(const short8*)(K2lo + l * 16 + qsel * 8);
    floatx4 er = __builtin_amdgcn_mfma_f32_16x16x32_bf16(afrag, b1l, (floatx4){0.f, 0.f, 0.f, 0.f}, 0, 0, 0);
    er = __builtin_amdgcn_mfma_f32_16x16x32_bf16(afrag, b1h, er, 0, 0, 0);
    floatx4 ei = __builtin_amdgcn_mfma_f32_16x16x32_bf16(afrag, b2l, (floatx4){0.f, 0.f, 0.f, 0.f}, 0, 0, 0);
    ei = __builtin_amdgcn_mfma_f32_16x16x32_bf16(afrag, b2h, ei, 0, 0, 0);
#pragma unroll
    for (int r = 0; r < 4; ++r) {
      float e = er[r] * er[r];
      e = fmaf(ei[r], ei[r], e);
      const float wgt = __expf(e - Mv[r]);
      sum[r] += wgt;
      att[(kb + m16 + quad * 4 + r) * Lc + l0 + lrow] = f2bf(wgt);
    }
  }
#pragma unroll
  for (int r = 0; r < 4; ++r) {
    float v = sum[r];
#pragma unroll
    for (int off = 1; off < 16; off <<= 1) v += __shfl_xor(v, off);
    if (lrow == 0) atomicAdd(&Ssum[kb + m16 + quad * 4 + r], v);
  }
}

// ---------------------------------------------------------------------------
// Phase 5: PV GEMM — DMA-staged single-barrier pipeline:
//   * 512 threads = 8 waves, split-K: group g = wid>>2 computes k-half g
//     (cb = 4g) of each staged 64-K tile; LDS reads stay square-optimal.
//   * Staging via __builtin_amdgcn_global_load_lds (16B): per phase each
//     wave issues 4 DMA chunks filling the NEXT 32 KB buffer (A 128x64 +
//     B 128x64) while computing the CURRENT one -> write traffic overlaps
//     compute, no register round-trip, ONE __syncthreads per phase.
//   * Swizzle both-sides (rule 21): DMA dest linear (base + lane*16);
//     global source chunk = (lane&7) ^ (lane>>3) (inverse of the read
//     swizzle) -> LDS contents identical to the verified r3 kernel; the
//     swizzled ds_read (measured conflict-free) is unchanged.
//   * 2 buffers x 32 KB = 64 KB static LDS; 64 phases of K=64.
//   * Final split-K reduction through LDS; epilogue out=(gamma/Ssum)*acc+x.
//   * XCD-aware bijective block swizzle (256 blocks % 8 == 0).
// ---------------------------------------------------------------------------
__device__ __forceinline__ void pv_stage(const unsigned short* __restrict__ vsrc,
                                         const unsigned short* __restrict__ asrc,
                                         short* lds_buf, int k0, int wid, int lane) {
  const int rsub = lane >> 3;          // 0..7: row within 8-row chunk
  const int ch   = (lane & 7) ^ rsub;  // inverse-swizzled global k-chunk
#pragma unroll
  for (int t = 0; t < 4; ++t) {
    const int q    = wid * 4 + t;      // chunk id 0..31 (1 KB each)
    const int tile = q >> 4;           // 0 = A(v), 1 = B(att)
    const int j    = q & 15;           // 8-row group within tile
    const int row  = j * 8 + rsub;
    const unsigned short* g =
        (tile == 0 ? vsrc : asrc) + (size_t)row * Lc + k0 + ch * 8;
    short* l = lds_buf + tile * 8192 + j * 512;  // wave-uniform dest base
    __builtin_amdgcn_global_load_lds(
        (const __attribute__((address_space(1))) void*)g,
        (__attribute__((address_space(3))) void*)l, 16, 0, 0);
  }
}

__device__ __forceinline__ void pv_compute32(const short* __restrict__ As,
                                             const short* __restrict__ Bs,
                                             int cb, int wcc, int wm, int lrow, int quad,
                                             floatx4 (&acc)[4][4]) {
  short8 af[4], bf[4];
#pragma unroll
  for (int i = 0; i < 4; ++i)
    af[i] = *(const short8*)&As[(wcc + i * 16 + lrow) * 64 +
                                ((cb + quad) ^ (lrow & 7)) * 8];
#pragma unroll
  for (int j = 0; j < 4; ++j)
    bf[j] = *(const short8*)&Bs[(wm + j * 16 + lrow) * 64 +
                                ((cb + quad) ^ (lrow & 7)) * 8];
#pragma unroll
  for (int i = 0; i < 4; ++i)
#pragma unroll
    for (int j = 0; j < 4; ++j)
      acc[i][j] = __builtin_amdgcn_mfma_f32_16x16x32_bf16(af[i], bf[j], acc[i][j], 0, 0, 0);
}

__global__ __launch_bounds__(512, 2) void pv_gemm(const unsigned short* __restrict__ v,
                                                  const unsigned short* __restrict__ att,
                                                  const float* __restrict__ Ssum,
                                                  const float* __restrict__ x,
                                                  const float* __restrict__ gamma,
                                                  float* __restrict__ out) {
  // 64 KB: buf0 {A 128x64 | B 128x64} | buf1 {A | B}, XOR-swizzled chunks.
  __shared__ short smem[2 * 2 * 128 * 64];
  // XCD-aware bijective swizzle: 256 blocks, XCD k gets contiguous work ids.
  const int flat = blockIdx.x;
  const int swz  = (flat & 7) * 32 + (flat >> 3);
  const int b    = swz >> 7;
  const int rem  = swz & 127;
  const int m0   = (rem >> 2) * 128;   // 32 m-panels
  const int cc0  = (rem & 3) * 128;    // 4 cc-panels
  const int tid  = threadIdx.x;
  const int wid  = tid >> 6, lane = tid & 63;
  const int g    = wid >> 2;           // split-K group: k-half of each tile
  const int w4   = wid & 3;
  const int wcc  = (w4 >> 1) * 64;
  const int wm   = (w4 & 1) * 64;
  const int lrow = lane & 15, quad = lane >> 4;
  const int cb   = g * 4;              // k-chunk base for this group
  floatx4 acc[4][4] = {};
  const unsigned short* vsrc = v   + ((size_t)b * 512 + cc0) * Lc;
  const unsigned short* asrc = att + ((size_t)b * Lc + m0) * Lc;
  // Prologue: DMA tile 0 into buf0.
  pv_stage(vsrc, asrc, smem, 0, wid, lane);
  asm volatile("s_waitcnt vmcnt(0)");
  __syncthreads();
  for (int p = 0; p < 64; ++p) {
    const int cur = p & 1;
    if (p + 1 < 64)
      pv_stage(vsrc, asrc, smem + (cur ^ 1) * 16384, (p + 1) * 64, wid, lane);
    pv_compute32(smem + cur * 16384, smem + cur * 16384 + 8192,
                 cb, wcc, wm, lrow, quad, acc);
    asm volatile("s_waitcnt vmcnt(0)");
    __syncthreads();
  }
  // Split-K reduction: group 1 -> LDS (XOR-swizzled floatx4, conflict-free),
  // group 0 adds and runs the epilogue.
  float* red = (float*)smem;  // 16384 floats = 64 KB
  if (g == 1) {
#pragma unroll
    for (int i = 0; i < 4; ++i)
#pragma unroll
      for (int j = 0; j < 4; ++j) {
        const int tq = i * 4 + j;
        *(floatx4*)&red[((w4 * 64 + lane) * 16 + (tq ^ (lane & 15))) * 4] = acc[i][j];
      }
  }
  __syncthreads();
  if (g == 0) {
#pragma unroll
    for (int i = 0; i < 4; ++i)
#pragma unroll
      for (int j = 0; j < 4; ++j) {
        const int tq = i * 4 + j;
        const floatx4 o = *(const floatx4*)&red[((w4 * 64 + lane) * 16 + (tq ^ (lane & 15))) * 4];
        acc[i][j] += o;
      }
    const float gm = gamma[0];
    float svj[4];
#pragma unroll
    for (int j = 0; j < 4; ++j)
      svj[j] = gm / Ssum[(size_t)b * Lc + m0 + wm + j * 16 + lrow];
#pragma unroll
    for (int i = 0; i < 4; ++i) {
      const int ccb = cc0 + wcc + i * 16 + quad * 4;
#pragma unroll
      for (int j = 0; j < 4; ++j) {
        const int m = m0 + wm + j * 16 + lrow;
#pragma unroll
        for (int rg = 0; rg < 4; ++rg) {
          const int cc   = ccb + rg;
          const int comp = cc >> 8, c = cc & 255;
          const size_t idx = (((size_t)comp * Bc + b) * CGc + c) * Lc + m;
          out[idx] = svj[j] * acc[i][j][rg] + x[idx];
        }
      }
    }
  }
}

// ---------------------------------------------------------------------------
extern "C" void kernel_launch(void* const* d_in, const int* in_sizes, int n_in,
                              void* d_out, int out_size, void* d_ws, size_t ws_size,
                              hipStream_t stream) {
  const float* x     = (const float*)d_in[0];
  const float* wq    = (const float*)d_in[1];
  const float* wk    = (const float*)d_in[2];
  const float* wv    = (const float*)d_in[3];
  const float* gamma = (const float*)d_in[4];
  float* out = (float*)d_out;

  // Workspace (~78.7 MB). Xlk aliases att (stream-ordered: v_gemm reads Xlk
  // before e_exp overwrites the region with att).
  float* q    = (float*)d_ws;                         // 131072
  float* kk   = q    + (size_t)Bc * Lc * 16;          // 131072
  float* Mrow = kk   + (size_t)Bc * Lc * 16;          // 8192  } contiguous:
  float* Ssum = Mrow + (size_t)Bc * Lc;               // 8192  } init zeroes both
  unsigned short* vbf  = (unsigned short*)(Ssum + (size_t)Bc * Lc);  // 2*512*4096
  unsigned short* att  = vbf + (size_t)Bc * 512 * Lc;                // 2*4096*4096
  unsigned short* Xlk  = att;                                        // alias (8.4MB)
  unsigned short* Qcat = att + (size_t)Bc * Lc * Lc;                 // 8192*32
  unsigned short* K1hi = Qcat + (size_t)Bc * Lc * 32;                // 8192*16
  unsigned short* K1lo = K1hi + (size_t)Bc * Lc * 16;
  unsigned short* K2hi = K1lo + (size_t)Bc * Lc * 16;
  unsigned short* K2lo = K2hi + (size_t)Bc * Lc * 16;
  unsigned short* Wcat = K2lo + (size_t)Bc * Lc * 16;                // 512*512

  init_stats<<<dim3((2 * Bc * Lc) / 256), 256, 0, stream>>>(Mrow);
  wcat_pack<<<dim3((512 * 512) / 256), 256, 0, stream>>>(wv, Wcat);
  qk_proj<<<dim3(Lc / 32, Bc), 256, 0, stream>>>(x, wq, wk, q, kk);
  qk_pack<<<dim3((Bc * Lc) / 256), 256, 0, stream>>>(q, kk, Qcat, K1hi, K1lo, K2hi, K2lo);
  xT_pack<<<dim3(Lc / 64, 8, Bc), 256, 0, stream>>>(x, Xlk);
  v_gemm<<<dim3(512 / 128, Lc / 64, Bc), 256, 0, stream>>>(Wcat, Xlk, vbf);
  e_max<<<dim3(Lc / 64, 8, Bc), 256, 0, stream>>>(Qcat, K1hi, K2hi, Mrow);
  e_exp<<<dim3(Lc / 64, 8, Bc), 256, 0, stream>>>(Qcat, K1hi, K1lo, K2hi, K2lo, Mrow, att, Ssum);
  pv_gemm<<<dim3(256), 512, 0, stream>>>(vbf, att, Ssum, x, gamma, out);
}

// Round 5
// 202.521 us; speedup vs baseline: 1.0311x; 1.0311x over previous
//
#include <hip/hip_runtime.h>
#include <cstdint>

// Shapes (fixed by the problem): B=2, C=64, G=4 -> CG=256, DQK=8, L=64*64=4096
constexpr int Bc  = 2;
constexpr int CGc = 256;
constexpr int Dc  = 8;
constexpr int Lc  = 4096;

typedef __attribute__((ext_vector_type(8))) short short8;
typedef __attribute__((ext_vector_type(4))) float floatx4;

__device__ inline unsigned short f2bf(float f) {
  union { float f; unsigned u; } v; v.f = f;
  unsigned r = v.u + 0x7fffu + ((v.u >> 16) & 1u);
  return (unsigned short)(r >> 16);
}
__device__ inline float bf2f(unsigned short h) {
  return __uint_as_float((unsigned)h << 16);
}

// ---------------------------------------------------------------------------
// Phase -1: zero Mrow(8192) + Ssum(8192) — contiguous 16384 floats.
// ---------------------------------------------------------------------------
__global__ __launch_bounds__(256) void init_stats(float* __restrict__ p) {
  p[blockIdx.x * 256 + threadIdx.x] = 0.f;
}

// ---------------------------------------------------------------------------
// Phase 0: Wcat[cc][k] bf16 = [[Wr, -Wi], [Wi, Wr]] (512x512) for v_gemm.
// ---------------------------------------------------------------------------
__global__ __launch_bounds__(256) void wcat_pack(const float* __restrict__ wv,
                                                 unsigned short* __restrict__ Wcat) {
  const int i  = blockIdx.x * 256 + threadIdx.x;  // 0..262143
  const int cc = i >> 9, k = i & 511;
  const int co = cc >> 8, c = cc & 255, ci = k >> 8, cin = k & 255;
  const float wr = wv[(size_t)c * CGc + cin];
  const float wi = wv[(size_t)(CGc + c) * CGc + cin];
  const float val = co == 0 ? (ci == 0 ? wr : -wi) : (ci == 0 ? wi : wr);
  Wcat[i] = f2bf(val);
}

// ---------------------------------------------------------------------------
// Phase 0b: LDS-transpose x -> Xlk[b][l][cin2] bf16 (cin2 = comp*256+cin).
// ---------------------------------------------------------------------------
__global__ __launch_bounds__(256) void xT_pack(const float* __restrict__ x,
                                               unsigned short* __restrict__ Xlk) {
  __shared__ float xs[64][65];
  const int tid = threadIdx.x;
  const int b   = blockIdx.z;
  const int l0  = blockIdx.x * 64;
  const int c0  = blockIdx.y * 64;
  const int lt  = tid & 63, r4 = tid >> 6;
#pragma unroll
  for (int p = 0; p < 16; ++p) {
    const int row  = p * 4 + r4;
    const int cin2 = c0 + row;
    const int comp = cin2 >> 8, cin = cin2 & 255;
    xs[row][lt] = x[((size_t)(comp * Bc + b) * CGc + cin) * Lc + l0 + lt];
  }
  __syncthreads();
#pragma unroll
  for (int p = 0; p < 16; ++p) {
    const int lr = p * 4 + r4;
    Xlk[((size_t)b * Lc + l0 + lr) * 512 + c0 + lt] = f2bf(xs[lt][lr]);
  }
}

// ---------------------------------------------------------------------------
// Phase 1: complex Q AND K projections in one pass (x read once, fp32).
// ---------------------------------------------------------------------------
__global__ __launch_bounds__(256) void qk_proj(const float* __restrict__ x,
                                               const float* __restrict__ wq,
                                               const float* __restrict__ wk,
                                               float* __restrict__ qout,
                                               float* __restrict__ kout) {
  __shared__ float ws[4 * Dc * CGc];  // 32 KB: wq_r | wq_i | wk_r | wk_i
  const int tid = threadIdx.x;
  const int b   = blockIdx.y;
  for (int i = tid; i < 2 * Dc * CGc; i += 256) {
    ws[i]                 = wq[i];
    ws[2 * Dc * CGc + i]  = wk[i];
  }
  __syncthreads();
  const int d  = tid >> 5;   // 0..7
  const int ml = tid & 31;   // 0..31
  const int m  = blockIdx.x * 32 + ml;
  const float* xr = x + ((size_t)(0 * Bc + b) * CGc) * Lc + m;
  const float* xi = x + ((size_t)(1 * Bc + b) * CGc) * Lc + m;
  const float* wqr = ws + d * CGc;
  const float* wqi = ws + (Dc + d) * CGc;
  const float* wkr = ws + 2 * Dc * CGc + d * CGc;
  const float* wki = ws + 2 * Dc * CGc + (Dc + d) * CGc;
  float qer = 0.f, qei = 0.f, ker = 0.f, kei = 0.f;
#pragma unroll 4
  for (int cin = 0; cin < CGc; ++cin) {
    const float vr = xr[(size_t)cin * Lc];
    const float vi = xi[(size_t)cin * Lc];
    const float a1 = wqr[cin], b1 = wqi[cin];
    qer = fmaf(a1, vr, qer); qer = fmaf(-b1, vi, qer);
    qei = fmaf(a1, vi, qei); qei = fmaf(b1, vr, qei);
    const float a2 = wkr[cin], b2 = wki[cin];
    ker = fmaf(a2, vr, ker); ker = fmaf(-b2, vi, ker);
    kei = fmaf(a2, vi, kei); kei = fmaf(b2, vr, kei);
  }
  float* qp = qout + ((size_t)b * Lc + m) * 16;
  qp[d]     = qer;
  qp[8 + d] = qei;
  float* kp = kout + ((size_t)b * Lc + m) * 16;
  kp[d]     = ker;
  kp[8 + d] = kei;
}

// ---------------------------------------------------------------------------
// Phase 1b: split-bf16 packing for MFMA QK^T.
//   Qcat [r][32] = [bf16hi(q~), bf16lo(q~)]   (q~ = [qr(8), qi(8)])
//   K1hi/K1lo [r][16] for k~1=[kr,-ki];  K2hi/K2lo for k~2=[ki,kr].
// er = q~.k~1 via 2 chained MFMAs (lo dup'd across quads: extra qlo.klo term
// is ~2^-18, harmless). One thread per row r = b*L+m.
// ---------------------------------------------------------------------------
__global__ __launch_bounds__(256) void qk_pack(const float* __restrict__ q,
                                               const float* __restrict__ k,
                                               unsigned short* __restrict__ Qcat,
                                               unsigned short* __restrict__ K1hi,
                                               unsigned short* __restrict__ K1lo,
                                               unsigned short* __restrict__ K2hi,
                                               unsigned short* __restrict__ K2lo) {
  const int r = blockIdx.x * 256 + threadIdx.x;  // 0..8191
  {
    const float* qp = q + (size_t)r * 16;
    unsigned u[16];
#pragma unroll
    for (int t = 0; t < 8; ++t) {
      const float v0 = qp[2 * t], v1 = qp[2 * t + 1];
      const unsigned short h0 = f2bf(v0), h1 = f2bf(v1);
      u[t] = (unsigned)h0 | ((unsigned)h1 << 16);
      const unsigned short l0 = f2bf(v0 - bf2f(h0));
      const unsigned short l1 = f2bf(v1 - bf2f(h1));
      u[8 + t] = (unsigned)l0 | ((unsigned)l1 << 16);
    }
    uint4* dst = (uint4*)(Qcat + (size_t)r * 32);
    dst[0] = make_uint4(u[0], u[1], u[2], u[3]);
    dst[1] = make_uint4(u[4], u[5], u[6], u[7]);
    dst[2] = make_uint4(u[8], u[9], u[10], u[11]);
    dst[3] = make_uint4(u[12], u[13], u[14], u[15]);
  }
  {
    const float* kp = k + (size_t)r * 16;
    float k1[16], k2[16];
#pragma unroll
    for (int d = 0; d < 8; ++d) {
      const float kr = kp[d], ki = kp[8 + d];
      k1[d] = kr;  k1[8 + d] = -ki;
      k2[d] = ki;  k2[8 + d] = kr;
    }
    unsigned uh[8], ul[8];
#pragma unroll
    for (int t = 0; t < 8; ++t) {
      const unsigned short h0 = f2bf(k1[2 * t]), h1 = f2bf(k1[2 * t + 1]);
      uh[t] = (unsigned)h0 | ((unsigned)h1 << 16);
      const unsigned short l0 = f2bf(k1[2 * t] - bf2f(h0));
      const unsigned short l1 = f2bf(k1[2 * t + 1] - bf2f(h1));
      ul[t] = (unsigned)l0 | ((unsigned)l1 << 16);
    }
    uint4* dh = (uint4*)(K1hi + (size_t)r * 16);
    dh[0] = make_uint4(uh[0], uh[1], uh[2], uh[3]);
    dh[1] = make_uint4(uh[4], uh[5], uh[6], uh[7]);
    uint4* dl = (uint4*)(K1lo + (size_t)r * 16);
    dl[0] = make_uint4(ul[0], ul[1], ul[2], ul[3]);
    dl[1] = make_uint4(ul[4], ul[5], ul[6], ul[7]);
#pragma unroll
    for (int t = 0; t < 8; ++t) {
      const unsigned short h0 = f2bf(k2[2 * t]), h1 = f2bf(k2[2 * t + 1]);
      uh[t] = (unsigned)h0 | ((unsigned)h1 << 16);
      const unsigned short l0 = f2bf(k2[2 * t] - bf2f(h0));
      const unsigned short l1 = f2bf(k2[2 * t + 1] - bf2f(h1));
      ul[t] = (unsigned)l0 | ((unsigned)l1 << 16);
    }
    uint4* dh2 = (uint4*)(K2hi + (size_t)r * 16);
    dh2[0] = make_uint4(uh[0], uh[1], uh[2], uh[3]);
    dh2[1] = make_uint4(uh[4], uh[5], uh[6], uh[7]);
    uint4* dl2 = (uint4*)(K2lo + (size_t)r * 16);
    dl2[0] = make_uint4(ul[0], ul[1], ul[2], ul[3]);
    dl2[1] = make_uint4(ul[4], ul[5], ul[6], ul[7]);
  }
}

// ---------------------------------------------------------------------------
// Phase 2: V projection as bf16 MFMA GEMM: v[cc][l] = sum_k Wcat[cc][k]*Xlk[l][k].
// Same swizzled+pipelined structure as before; K=512.
// ---------------------------------------------------------------------------
__global__ __launch_bounds__(256) void v_gemm(const unsigned short* __restrict__ Wcat,
                                              const unsigned short* __restrict__ Xlk,
                                              unsigned short* __restrict__ vbf) {
  __shared__ short As[128 * 64];
  __shared__ short Bs[64 * 64];
  const int tid  = threadIdx.x;
  const int b    = blockIdx.z;
  const int cc0  = blockIdx.x * 128;
  const int l0   = blockIdx.y * 64;
  const int wid  = tid >> 6, lane = tid & 63;
  const int wcc  = (wid >> 1) * 64;
  const int wl   = (wid & 1) * 32;
  const int lrow = lane & 15, quad = lane >> 4;
  floatx4 acc[4][2] = {};
  const unsigned short* wsrc = Wcat + (size_t)cc0 * 512;
  const unsigned short* xsrc = Xlk + ((size_t)b * Lc + l0) * 512;
  int s_off[4], g_off[4];
#pragma unroll
  for (int r = 0; r < 4; ++r) {
    const int idx = r * 256 + tid;
    const int row = idx >> 3, ch = idx & 7;
    s_off[r] = row * 64 + (ch ^ (row & 7)) * 8;
    g_off[r] = row * 512 + ch * 8;
  }
  short8 ar[4], br[2];
#pragma unroll
  for (int r = 0; r < 4; ++r) ar[r] = *(const short8*)(wsrc + g_off[r]);
#pragma unroll
  for (int r = 0; r < 2; ++r) br[r] = *(const short8*)(xsrc + g_off[r]);
  for (int k0 = 0; k0 < 512; k0 += 64) {
    __syncthreads();
#pragma unroll
    for (int r = 0; r < 4; ++r) *(short8*)&As[s_off[r]] = ar[r];
#pragma unroll
    for (int r = 0; r < 2; ++r) *(short8*)&Bs[s_off[r]] = br[r];
    __syncthreads();
    if (k0 + 64 < 512) {
#pragma unroll
      for (int r = 0; r < 4; ++r) ar[r] = *(const short8*)(wsrc + g_off[r] + k0 + 64);
#pragma unroll
      for (int r = 0; r < 2; ++r) br[r] = *(const short8*)(xsrc + g_off[r] + k0 + 64);
    }
#pragma unroll
    for (int kk = 0; kk < 64; kk += 32) {
      const int cb = kk >> 3;  // 0 or 4
      short8 af[4], bf[2];
#pragma unroll
      for (int i = 0; i < 4; ++i)
        af[i] = *(const short8*)&As[(wcc + i * 16 + lrow) * 64 +
                                    ((cb + quad) ^ (lrow & 7)) * 8];
#pragma unroll
      for (int j = 0; j < 2; ++j)
        bf[j] = *(const short8*)&Bs[(wl + j * 16 + lrow) * 64 +
                                    ((cb + quad) ^ (lrow & 7)) * 8];
#pragma unroll
      for (int i = 0; i < 4; ++i)
#pragma unroll
        for (int j = 0; j < 2; ++j)
          acc[i][j] = __builtin_amdgcn_mfma_f32_16x16x32_bf16(af[i], bf[j], acc[i][j], 0, 0, 0);
    }
  }
#pragma unroll
  for (int i = 0; i < 4; ++i) {
    const int ccb = cc0 + wcc + i * 16 + quad * 4;
#pragma unroll
    for (int j = 0; j < 2; ++j) {
      const int l = l0 + wl + j * 16 + lrow;
#pragma unroll
      for (int rg = 0; rg < 4; ++rg)
        vbf[((size_t)b * 512 + ccb + rg) * Lc + l] = f2bf(acc[i][j][rg]);
    }
  }
}

// ---------------------------------------------------------------------------
// Phase 3: row max of E via MFMA QK^T, hi-only (shift needs only approx max:
// error <= E*2^-8 ~ 7 -> exp <= e^7, safe; shift cancels in normalization).
// ---------------------------------------------------------------------------
__global__ __launch_bounds__(256) void e_max(const unsigned short* __restrict__ Qcat,
                                             const unsigned short* __restrict__ K1hi,
                                             const unsigned short* __restrict__ K2hi,
                                             float* __restrict__ Mrow) {
  const int tid  = threadIdx.x;
  const int w    = tid >> 6, lane = tid & 63;
  const int lrow = lane & 15, quad = lane >> 4, qsel = quad & 1;
  const int b    = blockIdx.z;
  const int m16  = blockIdx.x * 64 + w * 16;
  const int lbeg = blockIdx.y * 512;
  const size_t kb = (size_t)b * Lc;
  const short8 afrag = *(const short8*)(Qcat + (kb + m16 + lrow) * 32 + quad * 8);
  float mx[4] = {0.f, 0.f, 0.f, 0.f};
  for (int l0 = lbeg; l0 < lbeg + 512; l0 += 16) {
    const size_t l = kb + l0 + lrow;
    const short8 b1h = *(const short8*)(K1hi + l * 16 + qsel * 8);
    const short8 b2h = *(const short8*)(K2hi + l * 16 + qsel * 8);
    const floatx4 er = __builtin_amdgcn_mfma_f32_16x16x32_bf16(afrag, b1h, (floatx4){0.f, 0.f, 0.f, 0.f}, 0, 0, 0);
    const floatx4 ei = __builtin_amdgcn_mfma_f32_16x16x32_bf16(afrag, b2h, (floatx4){0.f, 0.f, 0.f, 0.f}, 0, 0, 0);
#pragma unroll
    for (int r = 0; r < 4; ++r) {
      float e = er[r] * er[r];
      e = fmaf(ei[r], ei[r], e);
      mx[r] = fmaxf(mx[r], e);
    }
  }
#pragma unroll
  for (int r = 0; r < 4; ++r) {
    float v = mx[r];
#pragma unroll
    for (int off = 1; off < 16; off <<= 1) v = fmaxf(v, __shfl_xor(v, off));
    if (lrow == 0)
      atomicMax((unsigned*)&Mrow[kb + m16 + quad * 4 + r], __float_as_uint(v));
  }
}

// ---------------------------------------------------------------------------
// Phase 4: att[m][l] = bf16(__expf(E-M)) (unnormalized), refined split-bf16 E;
// partial row sums -> atomicAdd(Ssum).
// ---------------------------------------------------------------------------
__global__ __launch_bounds__(256) void e_exp(const unsigned short* __restrict__ Qcat,
                                             const unsigned short* __restrict__ K1hi,
                                             const unsigned short* __restrict__ K1lo,
                                             const unsigned short* __restrict__ K2hi,
                                             const unsigned short* __restrict__ K2lo,
                                             const float* __restrict__ Mrow,
                                             unsigned short* __restrict__ att,
                                             float* __restrict__ Ssum) {
  const int tid  = threadIdx.x;
  const int w    = tid >> 6, lane = tid & 63;
  const int lrow = lane & 15, quad = lane >> 4, qsel = quad & 1;
  const int b    = blockIdx.z;
  const int m16  = blockIdx.x * 64 + w * 16;
  const int lbeg = blockIdx.y * 512;
  const size_t kb = (size_t)b * Lc;
  const short8 afrag = *(const short8*)(Qcat + (kb + m16 + lrow) * 32 + quad * 8);
  float Mv[4], sum[4] = {};
#pragma unroll
  for (int r = 0; r < 4; ++r) Mv[r] = Mrow[kb + m16 + quad * 4 + r];
  for (int l0 = lbeg; l0 < lbeg + 512; l0 += 16) {
    const size_t l = kb + l0 + lrow;
    const short8 b1h = *(const short8*)(K1hi + l * 16 + qsel * 8);
    const short8 b1l = *(const short8*)(K1lo + l * 16 + qsel * 8);
    const short8 b2h = *(const short8*)(K2hi + l * 16 + qsel * 8);
    const short8 b2l = *(const short8*)(K2lo + l * 16 + qsel * 8);
    floatx4 er = __builtin_amdgcn_mfma_f32_16x16x32_bf16(afrag, b1l, (floatx4){0.f, 0.f, 0.f, 0.f}, 0, 0, 0);
    er = __builtin_amdgcn_mfma_f32_16x16x32_bf16(afrag, b1h, er, 0, 0, 0);
    floatx4 ei = __builtin_amdgcn_mfma_f32_16x16x32_bf16(afrag, b2l, (floatx4){0.f, 0.f, 0.f, 0.f}, 0, 0, 0);
    ei = __builtin_amdgcn_mfma_f32_16x16x32_bf16(afrag, b2h, ei, 0, 0, 0);
#pragma unroll
    for (int r = 0; r < 4; ++r) {
      float e = er[r] * er[r];
      e = fmaf(ei[r], ei[r], e);
      const float wgt = __expf(e - Mv[r]);
      sum[r] += wgt;
      att[(kb + m16 + quad * 4 + r) * Lc + l0 + lrow] = f2bf(wgt);
    }
  }
#pragma unroll
  for (int r = 0; r < 4; ++r) {
    float v = sum[r];
#pragma unroll
    for (int off = 1; off < 16; off <<= 1) v += __shfl_xor(v, off);
    if (lrow == 0) atomicAdd(&Ssum[kb + m16 + quad * 4 + r], v);
  }
}

// ---------------------------------------------------------------------------
// Phase 5: PV GEMM — 3-buffer distance-2 DMA pipeline (T3/T4):
//   * 512 threads = 8 waves, split-K: group g = wid>>2 computes k-half g
//     (cb = 4g) of each staged 64-K tile.
//   * 96 KB dynamic LDS = 3 x {A 128x64 | B 128x64} buffers.
//   * Phase p: issue DMA (global_load_lds) for tile p+2; s_waitcnt vmcnt(8)
//     (waits ONLY tile p; tiles p+1, p+2 = 8 loads/wave stay in flight
//     across the barrier); raw s_barrier; compute tile p; raw s_barrier
//     (protects buffer reuse, distance 3). Epilogue drains 8 -> 4 -> 0.
//   * Swizzle both-sides (rule 21): DMA dest linear, global source chunk
//     inverse-XOR-swizzled; swizzled ds_read unchanged (conflict-free,
//     byte-identical LDS contents to the verified round-4 kernel).
//   * Final split-K reduction through LDS; epilogue out=(gamma/Ssum)*acc+x.
//   * XCD-aware bijective block swizzle (256 blocks % 8 == 0).
// ---------------------------------------------------------------------------
__device__ __forceinline__ void pv_stage(const unsigned short* __restrict__ vsrc,
                                         const unsigned short* __restrict__ asrc,
                                         short* lds_buf, int k0, int wid, int lane) {
  const int rsub = lane >> 3;          // 0..7: row within 8-row chunk
  const int ch   = (lane & 7) ^ rsub;  // inverse-swizzled global k-chunk
#pragma unroll
  for (int t = 0; t < 4; ++t) {
    const int q    = wid * 4 + t;      // chunk id 0..31 (1 KB each)
    const int tile = q >> 4;           // 0 = A(v), 1 = B(att)
    const int j    = q & 15;           // 8-row group within tile
    const int row  = j * 8 + rsub;
    const unsigned short* g =
        (tile == 0 ? vsrc : asrc) + (size_t)row * Lc + k0 + ch * 8;
    short* l = lds_buf + tile * 8192 + j * 512;  // wave-uniform dest base
    __builtin_amdgcn_global_load_lds(
        (const __attribute__((address_space(1))) void*)g,
        (__attribute__((address_space(3))) void*)l, 16, 0, 0);
  }
}

__device__ __forceinline__ void pv_compute32(const short* __restrict__ As,
                                             const short* __restrict__ Bs,
                                             int cb, int wcc, int wm, int lrow, int quad,
                                             floatx4 (&acc)[4][4]) {
  short8 af[4], bf[4];
#pragma unroll
  for (int i = 0; i < 4; ++i)
    af[i] = *(const short8*)&As[(wcc + i * 16 + lrow) * 64 +
                                ((cb + quad) ^ (lrow & 7)) * 8];
#pragma unroll
  for (int j = 0; j < 4; ++j)
    bf[j] = *(const short8*)&Bs[(wm + j * 16 + lrow) * 64 +
                                ((cb + quad) ^ (lrow & 7)) * 8];
#pragma unroll
  for (int i = 0; i < 4; ++i)
#pragma unroll
    for (int j = 0; j < 4; ++j)
      acc[i][j] = __builtin_amdgcn_mfma_f32_16x16x32_bf16(af[i], bf[j], acc[i][j], 0, 0, 0);
}

__global__ __launch_bounds__(512, 2) void pv_gemm(const unsigned short* __restrict__ v,
                                                  const unsigned short* __restrict__ att,
                                                  const float* __restrict__ Ssum,
                                                  const float* __restrict__ x,
                                                  const float* __restrict__ gamma,
                                                  float* __restrict__ out) {
  // 96 KB dynamic: 3 buffers x {A 128x64 | B 128x64} bf16, XOR-swizzled.
  extern __shared__ short smem[];
  // XCD-aware bijective swizzle: 256 blocks, XCD k gets contiguous work ids.
  const int flat = blockIdx.x;
  const int swz  = (flat & 7) * 32 + (flat >> 3);
  const int b    = swz >> 7;
  const int rem  = swz & 127;
  const int m0   = (rem >> 2) * 128;   // 32 m-panels
  const int cc0  = (rem & 3) * 128;    // 4 cc-panels
  const int tid  = threadIdx.x;
  const int wid  = tid >> 6, lane = tid & 63;
  const int g    = wid >> 2;           // split-K group: k-half of each tile
  const int w4   = wid & 3;
  const int wcc  = (w4 >> 1) * 64;
  const int wm   = (w4 & 1) * 64;
  const int lrow = lane & 15, quad = lane >> 4;
  const int cb   = g * 4;              // k-chunk base for this group
  floatx4 acc[4][4] = {};
  const unsigned short* vsrc = v   + ((size_t)b * 512 + cc0) * Lc;
  const unsigned short* asrc = att + ((size_t)b * Lc + m0) * Lc;
  // Prologue: DMA tiles 0,1 into buffers 0,1 (8 loads/wave outstanding).
  pv_stage(vsrc, asrc, smem,          0, wid, lane);
  pv_stage(vsrc, asrc, smem + 16384, 64, wid, lane);
  int cur = 0;  // buffer holding tile p
  for (int p = 0; p < 64; ++p) {
    if (p + 2 < 64) {
      const int nxt = cur + 2 > 2 ? cur - 1 : cur + 2;  // (cur+2)%3
      pv_stage(vsrc, asrc, smem + nxt * 16384, (p + 2) * 64, wid, lane);
      asm volatile("s_waitcnt vmcnt(8)" ::: "memory");
    } else if (p + 1 < 64) {
      asm volatile("s_waitcnt vmcnt(4)" ::: "memory");
    } else {
      asm volatile("s_waitcnt vmcnt(0)" ::: "memory");
    }
    __builtin_amdgcn_s_barrier();          // tile p visible to all waves
    __builtin_amdgcn_sched_barrier(0);     // pin ds_reads below the barrier
    pv_compute32(smem + cur * 16384, smem + cur * 16384 + 8192,
                 cb, wcc, wm, lrow, quad, acc);
    __builtin_amdgcn_sched_barrier(0);     // pin ds_reads above the barrier
    __builtin_amdgcn_s_barrier();          // buffer may be overwritten next
    cur = cur + 1 > 2 ? 0 : cur + 1;
  }
  // Split-K reduction: group 1 -> LDS (XOR-swizzled floatx4, conflict-free),
  // group 0 adds and runs the epilogue.
  float* red = (float*)smem;  // 16384 floats = 64 KB
  if (g == 1) {
#pragma unroll
    for (int i = 0; i < 4; ++i)
#pragma unroll
      for (int j = 0; j < 4; ++j) {
        const int tq = i * 4 + j;
        *(floatx4*)&red[((w4 * 64 + lane) * 16 + (tq ^ (lane & 15))) * 4] = acc[i][j];
      }
  }
  __syncthreads();
  if (g == 0) {
#pragma unroll
    for (int i = 0; i < 4; ++i)
#pragma unroll
      for (int j = 0; j < 4; ++j) {
        const int tq = i * 4 + j;
        const floatx4 o = *(const floatx4*)&red[((w4 * 64 + lane) * 16 + (tq ^ (lane & 15))) * 4];
        acc[i][j] += o;
      }
    const float gm = gamma[0];
    float svj[4];
#pragma unroll
    for (int j = 0; j < 4; ++j)
      svj[j] = gm / Ssum[(size_t)b * Lc + m0 + wm + j * 16 + lrow];
#pragma unroll
    for (int i = 0; i < 4; ++i) {
      const int ccb = cc0 + wcc + i * 16 + quad * 4;
#pragma unroll
      for (int j = 0; j < 4; ++j) {
        const int m = m0 + wm + j * 16 + lrow;
#pragma unroll
        for (int rg = 0; rg < 4; ++rg) {
          const int cc   = ccb + rg;
          const int comp = cc >> 8, c = cc & 255;
          const size_t idx = (((size_t)comp * Bc + b) * CGc + c) * Lc + m;
          out[idx] = svj[j] * acc[i][j][rg] + x[idx];
        }
      }
    }
  }
}

// ---------------------------------------------------------------------------
extern "C" void kernel_launch(void* const* d_in, const int* in_sizes, int n_in,
                              void* d_out, int out_size, void* d_ws, size_t ws_size,
                              hipStream_t stream) {
  const float* x     = (const float*)d_in[0];
  const float* wq    = (const float*)d_in[1];
  const float* wk    = (const float*)d_in[2];
  const float* wv    = (const float*)d_in[3];
  const float* gamma = (const float*)d_in[4];
  float* out = (float*)d_out;

  // Workspace (~78.7 MB). Xlk aliases att (stream-ordered: v_gemm reads Xlk
  // before e_exp overwrites the region with att).
  float* q    = (float*)d_ws;                         // 131072
  float* kk   = q    + (size_t)Bc * Lc * 16;          // 131072
  float* Mrow = kk   + (size_t)Bc * Lc * 16;          // 8192  } contiguous:
  float* Ssum = Mrow + (size_t)Bc * Lc;               // 8192  } init zeroes both
  unsigned short* vbf  = (unsigned short*)(Ssum + (size_t)Bc * Lc);  // 2*512*4096
  unsigned short* att  = vbf + (size_t)Bc * 512 * Lc;                // 2*4096*4096
  unsigned short* Xlk  = att;                                        // alias (8.4MB)
  unsigned short* Qcat = att + (size_t)Bc * Lc * Lc;                 // 8192*32
  unsigned short* K1hi = Qcat + (size_t)Bc * Lc * 32;                // 8192*16
  unsigned short* K1lo = K1hi + (size_t)Bc * Lc * 16;
  unsigned short* K2hi = K1lo + (size_t)Bc * Lc * 16;
  unsigned short* K2lo = K2hi + (size_t)Bc * Lc * 16;
  unsigned short* Wcat = K2lo + (size_t)Bc * Lc * 16;                // 512*512

  init_stats<<<dim3((2 * Bc * Lc) / 256), 256, 0, stream>>>(Mrow);
  wcat_pack<<<dim3((512 * 512) / 256), 256, 0, stream>>>(wv, Wcat);
  qk_proj<<<dim3(Lc / 32, Bc), 256, 0, stream>>>(x, wq, wk, q, kk);
  qk_pack<<<dim3((Bc * Lc) / 256), 256, 0, stream>>>(q, kk, Qcat, K1hi, K1lo, K2hi, K2lo);
  xT_pack<<<dim3(Lc / 64, 8, Bc), 256, 0, stream>>>(x, Xlk);
  v_gemm<<<dim3(512 / 128, Lc / 64, Bc), 256, 0, stream>>>(Wcat, Xlk, vbf);
  e_max<<<dim3(Lc / 64, 8, Bc), 256, 0, stream>>>(Qcat, K1hi, K2hi, Mrow);
  e_exp<<<dim3(Lc / 64, 8, Bc), 256, 0, stream>>>(Qcat, K1hi, K1lo, K2hi, K2lo, Mrow, att, Ssum);
  pv_gemm<<<dim3(256), 512, 3 * 16384 * sizeof(short), stream>>>(vbf, att, Ssum, x, gamma, out);
}

// Round 6
// 194.572 us; speedup vs baseline: 1.0733x; 1.0409x over previous
//
#include <hip/hip_runtime.h>
#include <cstdint>

// Shapes (fixed by the problem): B=2, C=64, G=4 -> CG=256, DQK=8, L=64*64=4096
constexpr int Bc  = 2;
constexpr int CGc = 256;
constexpr int Dc  = 8;
constexpr int Lc  = 4096;

typedef __attribute__((ext_vector_type(8))) short short8;
typedef __attribute__((ext_vector_type(4))) float floatx4;

__device__ inline unsigned short f2bf(float f) {
  union { float f; unsigned u; } v; v.f = f;
  unsigned r = v.u + 0x7fffu + ((v.u >> 16) & 1u);
  return (unsigned short)(r >> 16);
}
__device__ inline float bf2f(unsigned short h) {
  return __uint_as_float((unsigned)h << 16);
}

// ---------------------------------------------------------------------------
// Phase -1/0 merged: blocks 0..63 zero Mrow+Ssum (16384 floats); blocks
// 64..1087 pack Wcat[cc][k] bf16 = [[Wr, -Wi], [Wi, Wr]] (512x512).
// ---------------------------------------------------------------------------
__global__ __launch_bounds__(256) void init_wcat(float* __restrict__ stats,
                                                 const float* __restrict__ wv,
                                                 unsigned short* __restrict__ Wcat) {
  const int bx = blockIdx.x;
  if (bx < 64) {
    stats[bx * 256 + threadIdx.x] = 0.f;
    return;
  }
  const int i  = (bx - 64) * 256 + threadIdx.x;  // 0..262143
  const int cc = i >> 9, k = i & 511;
  const int co = cc >> 8, c = cc & 255, ci = k >> 8, cin = k & 255;
  const float wr = wv[(size_t)c * CGc + cin];
  const float wi = wv[(size_t)(CGc + c) * CGc + cin];
  const float val = co == 0 ? (ci == 0 ? wr : -wi) : (ci == 0 ? wi : wr);
  Wcat[i] = f2bf(val);
}

// ---------------------------------------------------------------------------
// Phase 0b: LDS-transpose x -> Xlk[b][l][cin2] bf16 (cin2 = comp*256+cin).
// ---------------------------------------------------------------------------
__global__ __launch_bounds__(256) void xT_pack(const float* __restrict__ x,
                                               unsigned short* __restrict__ Xlk) {
  __shared__ float xs[64][65];
  const int tid = threadIdx.x;
  const int b   = blockIdx.z;
  const int l0  = blockIdx.x * 64;
  const int c0  = blockIdx.y * 64;
  const int lt  = tid & 63, r4 = tid >> 6;
#pragma unroll
  for (int p = 0; p < 16; ++p) {
    const int row  = p * 4 + r4;
    const int cin2 = c0 + row;
    const int comp = cin2 >> 8, cin = cin2 & 255;
    xs[row][lt] = x[((size_t)(comp * Bc + b) * CGc + cin) * Lc + l0 + lt];
  }
  __syncthreads();
#pragma unroll
  for (int p = 0; p < 16; ++p) {
    const int lr = p * 4 + r4;
    Xlk[((size_t)b * Lc + l0 + lr) * 512 + c0 + lt] = f2bf(xs[lt][lr]);
  }
}

// ---------------------------------------------------------------------------
// Phase 1 (fused): complex Q AND K projections + split-bf16 MFMA packing in
// one kernel. Projection identical to the verified qk_proj; results hand off
// through 4 KB LDS (fp32, bit-identical path) to the pack stage, which is
// the verified qk_pack math distributed over 8 thread-parts per row:
//   part0: Qcat hi | part1: Qcat lo | part2: K1hi | part3: K1lo
//   part4: K2hi    | part5: K2lo    | parts 6,7 idle.
// Kills the qk_pack launch and the 1 MB q/k global round-trip.
// ---------------------------------------------------------------------------
__global__ __launch_bounds__(256) void qk_projpack(const float* __restrict__ x,
                                                   const float* __restrict__ wq,
                                                   const float* __restrict__ wk,
                                                   unsigned short* __restrict__ Qcat,
                                                   unsigned short* __restrict__ K1hi,
                                                   unsigned short* __restrict__ K1lo,
                                                   unsigned short* __restrict__ K2hi,
                                                   unsigned short* __restrict__ K2lo) {
  __shared__ float ws[4 * Dc * CGc];  // 32 KB: wq_r | wq_i | wk_r | wk_i
  __shared__ float qs[32][16];        // 2 KB: q~ rows
  __shared__ float ks[32][16];        // 2 KB: k~ rows
  const int tid = threadIdx.x;
  const int b   = blockIdx.y;
  for (int i = tid; i < 2 * Dc * CGc; i += 256) {
    ws[i]                 = wq[i];
    ws[2 * Dc * CGc + i]  = wk[i];
  }
  __syncthreads();
  const int d  = tid >> 5;   // 0..7
  const int ml = tid & 31;   // 0..31
  const int m  = blockIdx.x * 32 + ml;
  const float* xr = x + ((size_t)(0 * Bc + b) * CGc) * Lc + m;
  const float* xi = x + ((size_t)(1 * Bc + b) * CGc) * Lc + m;
  const float* wqr = ws + d * CGc;
  const float* wqi = ws + (Dc + d) * CGc;
  const float* wkr = ws + 2 * Dc * CGc + d * CGc;
  const float* wki = ws + 2 * Dc * CGc + (Dc + d) * CGc;
  float qer = 0.f, qei = 0.f, ker = 0.f, kei = 0.f;
#pragma unroll 4
  for (int cin = 0; cin < CGc; ++cin) {
    const float vr = xr[(size_t)cin * Lc];
    const float vi = xi[(size_t)cin * Lc];
    const float a1 = wqr[cin], b1 = wqi[cin];
    qer = fmaf(a1, vr, qer); qer = fmaf(-b1, vi, qer);
    qei = fmaf(a1, vi, qei); qei = fmaf(b1, vr, qei);
    const float a2 = wkr[cin], b2 = wki[cin];
    ker = fmaf(a2, vr, ker); ker = fmaf(-b2, vi, ker);
    kei = fmaf(a2, vi, kei); kei = fmaf(b2, vr, kei);
  }
  qs[ml][d] = qer;  qs[ml][8 + d] = qei;
  ks[ml][d] = ker;  ks[ml][8 + d] = kei;
  __syncthreads();
  // --- pack stage ---
  const int part = tid >> 5;       // 0..7
  const int rl   = tid & 31;       // local row
  const size_t r = (size_t)b * Lc + blockIdx.x * 32 + rl;
  if (part < 2) {
    // Qcat: part0 = hi half [0..15], part1 = lo half [16..31]
    unsigned u[8];
#pragma unroll
    for (int t = 0; t < 8; ++t) {
      const float v0 = qs[rl][2 * t], v1 = qs[rl][2 * t + 1];
      const unsigned short h0 = f2bf(v0), h1 = f2bf(v1);
      if (part == 0) {
        u[t] = (unsigned)h0 | ((unsigned)h1 << 16);
      } else {
        const unsigned short l0 = f2bf(v0 - bf2f(h0));
        const unsigned short l1 = f2bf(v1 - bf2f(h1));
        u[t] = (unsigned)l0 | ((unsigned)l1 << 16);
      }
    }
    uint4* dst = (uint4*)(Qcat + r * 32 + part * 16);
    dst[0] = make_uint4(u[0], u[1], u[2], u[3]);
    dst[1] = make_uint4(u[4], u[5], u[6], u[7]);
  } else if (part < 6) {
    // part2: K1hi, part3: K1lo, part4: K2hi, part5: K2lo
    float kv[16];
    if (part < 4) {
#pragma unroll
      for (int e = 0; e < 8; ++e) { kv[e] = ks[rl][e]; kv[8 + e] = -ks[rl][8 + e]; }
    } else {
#pragma unroll
      for (int e = 0; e < 8; ++e) { kv[e] = ks[rl][8 + e]; kv[8 + e] = ks[rl][e]; }
    }
    const int lo = part & 1;  // 2:hi 3:lo 4:hi 5:lo
    unsigned u[8];
#pragma unroll
    for (int t = 0; t < 8; ++t) {
      const unsigned short h0 = f2bf(kv[2 * t]), h1 = f2bf(kv[2 * t + 1]);
      if (!lo) {
        u[t] = (unsigned)h0 | ((unsigned)h1 << 16);
      } else {
        const unsigned short l0 = f2bf(kv[2 * t] - bf2f(h0));
        const unsigned short l1 = f2bf(kv[2 * t + 1] - bf2f(h1));
        u[t] = (unsigned)l0 | ((unsigned)l1 << 16);
      }
    }
    unsigned short* base = part < 4 ? (lo ? K1lo : K1hi) : (lo ? K2lo : K2hi);
    uint4* dst = (uint4*)(base + r * 16);
    dst[0] = make_uint4(u[0], u[1], u[2], u[3]);
    dst[1] = make_uint4(u[4], u[5], u[6], u[7]);
  }
}

// ---------------------------------------------------------------------------
// Phase 2: V projection as bf16 MFMA GEMM: v[cc][l] = sum_k Wcat[cc][k]*Xlk[l][k].
// Same swizzled+pipelined structure as before; K=512.
// ---------------------------------------------------------------------------
__global__ __launch_bounds__(256) void v_gemm(const unsigned short* __restrict__ Wcat,
                                              const unsigned short* __restrict__ Xlk,
                                              unsigned short* __restrict__ vbf) {
  __shared__ short As[128 * 64];
  __shared__ short Bs[64 * 64];
  const int tid  = threadIdx.x;
  const int b    = blockIdx.z;
  const int cc0  = blockIdx.x * 128;
  const int l0   = blockIdx.y * 64;
  const int wid  = tid >> 6, lane = tid & 63;
  const int wcc  = (wid >> 1) * 64;
  const int wl   = (wid & 1) * 32;
  const int lrow = lane & 15, quad = lane >> 4;
  floatx4 acc[4][2] = {};
  const unsigned short* wsrc = Wcat + (size_t)cc0 * 512;
  const unsigned short* xsrc = Xlk + ((size_t)b * Lc + l0) * 512;
  int s_off[4], g_off[4];
#pragma unroll
  for (int r = 0; r < 4; ++r) {
    const int idx = r * 256 + tid;
    const int row = idx >> 3, ch = idx & 7;
    s_off[r] = row * 64 + (ch ^ (row & 7)) * 8;
    g_off[r] = row * 512 + ch * 8;
  }
  short8 ar[4], br[2];
#pragma unroll
  for (int r = 0; r < 4; ++r) ar[r] = *(const short8*)(wsrc + g_off[r]);
#pragma unroll
  for (int r = 0; r < 2; ++r) br[r] = *(const short8*)(xsrc + g_off[r]);
  for (int k0 = 0; k0 < 512; k0 += 64) {
    __syncthreads();
#pragma unroll
    for (int r = 0; r < 4; ++r) *(short8*)&As[s_off[r]] = ar[r];
#pragma unroll
    for (int r = 0; r < 2; ++r) *(short8*)&Bs[s_off[r]] = br[r];
    __syncthreads();
    if (k0 + 64 < 512) {
#pragma unroll
      for (int r = 0; r < 4; ++r) ar[r] = *(const short8*)(wsrc + g_off[r] + k0 + 64);
#pragma unroll
      for (int r = 0; r < 2; ++r) br[r] = *(const short8*)(xsrc + g_off[r] + k0 + 64);
    }
#pragma unroll
    for (int kk = 0; kk < 64; kk += 32) {
      const int cb = kk >> 3;  // 0 or 4
      short8 af[4], bf[2];
#pragma unroll
      for (int i = 0; i < 4; ++i)
        af[i] = *(const short8*)&As[(wcc + i * 16 + lrow) * 64 +
                                    ((cb + quad) ^ (lrow & 7)) * 8];
#pragma unroll
      for (int j = 0; j < 2; ++j)
        bf[j] = *(const short8*)&Bs[(wl + j * 16 + lrow) * 64 +
                                    ((cb + quad) ^ (lrow & 7)) * 8];
#pragma unroll
      for (int i = 0; i < 4; ++i)
#pragma unroll
        for (int j = 0; j < 2; ++j)
          acc[i][j] = __builtin_amdgcn_mfma_f32_16x16x32_bf16(af[i], bf[j], acc[i][j], 0, 0, 0);
    }
  }
#pragma unroll
  for (int i = 0; i < 4; ++i) {
    const int ccb = cc0 + wcc + i * 16 + quad * 4;
#pragma unroll
    for (int j = 0; j < 2; ++j) {
      const int l = l0 + wl + j * 16 + lrow;
#pragma unroll
      for (int rg = 0; rg < 4; ++rg)
        vbf[((size_t)b * 512 + ccb + rg) * Lc + l] = f2bf(acc[i][j][rg]);
    }
  }
}

// ---------------------------------------------------------------------------
// Phase 3: row max of E via MFMA QK^T, hi-only (shift needs only approx max:
// error <= E*2^-8 ~ 7 -> exp <= e^7, safe; shift cancels in normalization).
// ---------------------------------------------------------------------------
__global__ __launch_bounds__(256) void e_max(const unsigned short* __restrict__ Qcat,
                                             const unsigned short* __restrict__ K1hi,
                                             const unsigned short* __restrict__ K2hi,
                                             float* __restrict__ Mrow) {
  const int tid  = threadIdx.x;
  const int w    = tid >> 6, lane = tid & 63;
  const int lrow = lane & 15, quad = lane >> 4, qsel = quad & 1;
  const int b    = blockIdx.z;
  const int m16  = blockIdx.x * 64 + w * 16;
  const int lbeg = blockIdx.y * 512;
  const size_t kb = (size_t)b * Lc;
  const short8 afrag = *(const short8*)(Qcat + (kb + m16 + lrow) * 32 + quad * 8);
  float mx[4] = {0.f, 0.f, 0.f, 0.f};
  for (int l0 = lbeg; l0 < lbeg + 512; l0 += 16) {
    const size_t l = kb + l0 + lrow;
    const short8 b1h = *(const short8*)(K1hi + l * 16 + qsel * 8);
    const short8 b2h = *(const short8*)(K2hi + l * 16 + qsel * 8);
    const floatx4 er = __builtin_amdgcn_mfma_f32_16x16x32_bf16(afrag, b1h, (floatx4){0.f, 0.f, 0.f, 0.f}, 0, 0, 0);
    const floatx4 ei = __builtin_amdgcn_mfma_f32_16x16x32_bf16(afrag, b2h, (floatx4){0.f, 0.f, 0.f, 0.f}, 0, 0, 0);
#pragma unroll
    for (int r = 0; r < 4; ++r) {
      float e = er[r] * er[r];
      e = fmaf(ei[r], ei[r], e);
      mx[r] = fmaxf(mx[r], e);
    }
  }
#pragma unroll
  for (int r = 0; r < 4; ++r) {
    float v = mx[r];
#pragma unroll
    for (int off = 1; off < 16; off <<= 1) v = fmaxf(v, __shfl_xor(v, off));
    if (lrow == 0)
      atomicMax((unsigned*)&Mrow[kb + m16 + quad * 4 + r], __float_as_uint(v));
  }
}

// ---------------------------------------------------------------------------
// Phase 4: att[m][l] = bf16(__expf(E-M)) (unnormalized), refined split-bf16 E;
// partial row sums -> atomicAdd(Ssum).
// ---------------------------------------------------------------------------
__global__ __launch_bounds__(256) void e_exp(const unsigned short* __restrict__ Qcat,
                                             const unsigned short* __restrict__ K1hi,
                                             const unsigned short* __restrict__ K1lo,
                                             const unsigned short* __restrict__ K2hi,
                                             const unsigned short* __restrict__ K2lo,
                                             const float* __restrict__ Mrow,
                                             unsigned short* __restrict__ att,
                                             float* __restrict__ Ssum) {
  const int tid  = threadIdx.x;
  const int w    = tid >> 6, lane = tid & 63;
  const int lrow = lane & 15, quad = lane >> 4, qsel = quad & 1;
  const int b    = blockIdx.z;
  const int m16  = blockIdx.x * 64 + w * 16;
  const int lbeg = blockIdx.y * 512;
  const size_t kb = (size_t)b * Lc;
  const short8 afrag = *(const short8*)(Qcat + (kb + m16 + lrow) * 32 + quad * 8);
  float Mv[4], sum[4] = {};
#pragma unroll
  for (int r = 0; r < 4; ++r) Mv[r] = Mrow[kb + m16 + quad * 4 + r];
  for (int l0 = lbeg; l0 < lbeg + 512; l0 += 16) {
    const size_t l = kb + l0 + lrow;
    const short8 b1h = *(const short8*)(K1hi + l * 16 + qsel * 8);
    const short8 b1l = *(const short8*)(K1lo + l * 16 + qsel * 8);
    const short8 b2h = *(const short8*)(K2hi + l * 16 + qsel * 8);
    const short8 b2l = *(const short8*)(K2lo + l * 16 + qsel * 8);
    floatx4 er = __builtin_amdgcn_mfma_f32_16x16x32_bf16(afrag, b1l, (floatx4){0.f, 0.f, 0.f, 0.f}, 0, 0, 0);
    er = __builtin_amdgcn_mfma_f32_16x16x32_bf16(afrag, b1h, er, 0, 0, 0);
    floatx4 ei = __builtin_amdgcn_mfma_f32_16x16x32_bf16(afrag, b2l, (floatx4){0.f, 0.f, 0.f, 0.f}, 0, 0, 0);
    ei = __builtin_amdgcn_mfma_f32_16x16x32_bf16(afrag, b2h, ei, 0, 0, 0);
#pragma unroll
    for (int r = 0; r < 4; ++r) {
      float e = er[r] * er[r];
      e = fmaf(ei[r], ei[r], e);
      const float wgt = __expf(e - Mv[r]);
      sum[r] += wgt;
      att[(kb + m16 + quad * 4 + r) * Lc + l0 + lrow] = f2bf(wgt);
    }
  }
#pragma unroll
  for (int r = 0; r < 4; ++r) {
    float v = sum[r];
#pragma unroll
    for (int off = 1; off < 16; off <<= 1) v += __shfl_xor(v, off);
    if (lrow == 0) atomicAdd(&Ssum[kb + m16 + quad * 4 + r], v);
  }
}

// ---------------------------------------------------------------------------
// Phase 5: PV GEMM — 3-buffer distance-2 DMA pipeline, ONE barrier per phase:
//   phase p: vmcnt(4) [my tile-p chunks done; tiles p+1 in flight] ->
//   s_barrier [collectively tile p complete; all waves done computing p-1] ->
//   issue DMA tile p+2 into buf[(p+2)%3] = buf[(p-1)%3] (its readers all
//   finished before the barrier) -> compute tile p. Epilogue drains 4 -> 0.
//   Everything else (split-K groups, swizzle both-sides, reduction,
//   XCD block swizzle) identical to the verified round-5 kernel.
// ---------------------------------------------------------------------------
__device__ __forceinline__ void pv_stage(const unsigned short* __restrict__ vsrc,
                                         const unsigned short* __restrict__ asrc,
                                         short* lds_buf, int k0, int wid, int lane) {
  const int rsub = lane >> 3;          // 0..7: row within 8-row chunk
  const int ch   = (lane & 7) ^ rsub;  // inverse-swizzled global k-chunk
#pragma unroll
  for (int t = 0; t < 4; ++t) {
    const int q    = wid * 4 + t;      // chunk id 0..31 (1 KB each)
    const int tile = q >> 4;           // 0 = A(v), 1 = B(att)
    const int j    = q & 15;           // 8-row group within tile
    const int row  = j * 8 + rsub;
    const unsigned short* g =
        (tile == 0 ? vsrc : asrc) + (size_t)row * Lc + k0 + ch * 8;
    short* l = lds_buf + tile * 8192 + j * 512;  // wave-uniform dest base
    __builtin_amdgcn_global_load_lds(
        (const __attribute__((address_space(1))) void*)g,
        (__attribute__((address_space(3))) void*)l, 16, 0, 0);
  }
}

__device__ __forceinline__ void pv_compute32(const short* __restrict__ As,
                                             const short* __restrict__ Bs,
                                             int cb, int wcc, int wm, int lrow, int quad,
                                             floatx4 (&acc)[4][4]) {
  short8 af[4], bf[4];
#pragma unroll
  for (int i = 0; i < 4; ++i)
    af[i] = *(const short8*)&As[(wcc + i * 16 + lrow) * 64 +
                                ((cb + quad) ^ (lrow & 7)) * 8];
#pragma unroll
  for (int j = 0; j < 4; ++j)
    bf[j] = *(const short8*)&Bs[(wm + j * 16 + lrow) * 64 +
                                ((cb + quad) ^ (lrow & 7)) * 8];
#pragma unroll
  for (int i = 0; i < 4; ++i)
#pragma unroll
    for (int j = 0; j < 4; ++j)
      acc[i][j] = __builtin_amdgcn_mfma_f32_16x16x32_bf16(af[i], bf[j], acc[i][j], 0, 0, 0);
}

__global__ __launch_bounds__(512, 2) void pv_gemm(const unsigned short* __restrict__ v,
                                                  const unsigned short* __restrict__ att,
                                                  const float* __restrict__ Ssum,
                                                  const float* __restrict__ x,
                                                  const float* __restrict__ gamma,
                                                  float* __restrict__ out) {
  // 96 KB dynamic: 3 buffers x {A 128x64 | B 128x64} bf16, XOR-swizzled.
  extern __shared__ short smem[];
  // XCD-aware bijective swizzle: 256 blocks, XCD k gets contiguous work ids.
  const int flat = blockIdx.x;
  const int swz  = (flat & 7) * 32 + (flat >> 3);
  const int b    = swz >> 7;
  const int rem  = swz & 127;
  const int m0   = (rem >> 2) * 128;   // 32 m-panels
  const int cc0  = (rem & 3) * 128;    // 4 cc-panels
  const int tid  = threadIdx.x;
  const int wid  = tid >> 6, lane = tid & 63;
  const int g    = wid >> 2;           // split-K group: k-half of each tile
  const int w4   = wid & 3;
  const int wcc  = (w4 >> 1) * 64;
  const int wm   = (w4 & 1) * 64;
  const int lrow = lane & 15, quad = lane >> 4;
  const int cb   = g * 4;              // k-chunk base for this group
  floatx4 acc[4][4] = {};
  const unsigned short* vsrc = v   + ((size_t)b * 512 + cc0) * Lc;
  const unsigned short* asrc = att + ((size_t)b * Lc + m0) * Lc;
  // Prologue: DMA tiles 0,1 into buffers 0,1 (8 loads/wave outstanding).
  pv_stage(vsrc, asrc, smem,          0, wid, lane);
  pv_stage(vsrc, asrc, smem + 16384, 64, wid, lane);
  int cur = 0;  // buffer holding tile p
  for (int p = 0; p < 64; ++p) {
    if (p < 63) {
      asm volatile("s_waitcnt vmcnt(4)" ::: "memory");   // my tile-p chunks done
    } else {
      asm volatile("s_waitcnt vmcnt(0)" ::: "memory");
    }
    __builtin_amdgcn_s_barrier();       // tile p complete; p-1 compute done
    __builtin_amdgcn_sched_barrier(0);
    if (p + 2 < 64) {
      const int nxt = cur + 2 > 2 ? cur - 1 : cur + 2;   // (cur+2)%3
      pv_stage(vsrc, asrc, smem + nxt * 16384, (p + 2) * 64, wid, lane);
    }
    __builtin_amdgcn_sched_barrier(0);
    pv_compute32(smem + cur * 16384, smem + cur * 16384 + 8192,
                 cb, wcc, wm, lrow, quad, acc);
    __builtin_amdgcn_sched_barrier(0);
    cur = cur + 1 > 2 ? 0 : cur + 1;
  }
  __syncthreads();  // all computes done before smem reuse for reduction
  // Split-K reduction: group 1 -> LDS (XOR-swizzled floatx4, conflict-free),
  // group 0 adds and runs the epilogue.
  float* red = (float*)smem;  // 16384 floats = 64 KB
  if (g == 1) {
#pragma unroll
    for (int i = 0; i < 4; ++i)
#pragma unroll
      for (int j = 0; j < 4; ++j) {
        const int tq = i * 4 + j;
        *(floatx4*)&red[((w4 * 64 + lane) * 16 + (tq ^ (lane & 15))) * 4] = acc[i][j];
      }
  }
  __syncthreads();
  if (g == 0) {
#pragma unroll
    for (int i = 0; i < 4; ++i)
#pragma unroll
      for (int j = 0; j < 4; ++j) {
        const int tq = i * 4 + j;
        const floatx4 o = *(const floatx4*)&red[((w4 * 64 + lane) * 16 + (tq ^ (lane & 15))) * 4];
        acc[i][j] += o;
      }
    const float gm = gamma[0];
    float svj[4];
#pragma unroll
    for (int j = 0; j < 4; ++j)
      svj[j] = gm / Ssum[(size_t)b * Lc + m0 + wm + j * 16 + lrow];
#pragma unroll
    for (int i = 0; i < 4; ++i) {
      const int ccb = cc0 + wcc + i * 16 + quad * 4;
#pragma unroll
      for (int j = 0; j < 4; ++j) {
        const int m = m0 + wm + j * 16 + lrow;
#pragma unroll
        for (int rg = 0; rg < 4; ++rg) {
          const int cc   = ccb + rg;
          const int comp = cc >> 8, c = cc & 255;
          const size_t idx = (((size_t)comp * Bc + b) * CGc + c) * Lc + m;
          out[idx] = svj[j] * acc[i][j][rg] + x[idx];
        }
      }
    }
  }
}

// ---------------------------------------------------------------------------
extern "C" void kernel_launch(void* const* d_in, const int* in_sizes, int n_in,
                              void* d_out, int out_size, void* d_ws, size_t ws_size,
                              hipStream_t stream) {
  const float* x     = (const float*)d_in[0];
  const float* wq    = (const float*)d_in[1];
  const float* wk    = (const float*)d_in[2];
  const float* wv    = (const float*)d_in[3];
  const float* gamma = (const float*)d_in[4];
  float* out = (float*)d_out;

  // Workspace (~78.7 MB). Xlk aliases att (stream-ordered: v_gemm reads Xlk
  // before e_exp overwrites the region with att). q/kk slots retained for
  // layout stability (unused since the qk fusion).
  float* q    = (float*)d_ws;                         // 131072 (unused)
  float* kk   = q    + (size_t)Bc * Lc * 16;          // 131072 (unused)
  float* Mrow = kk   + (size_t)Bc * Lc * 16;          // 8192  } contiguous:
  float* Ssum = Mrow + (size_t)Bc * Lc;               // 8192  } init zeroes both
  unsigned short* vbf  = (unsigned short*)(Ssum + (size_t)Bc * Lc);  // 2*512*4096
  unsigned short* att  = vbf + (size_t)Bc * 512 * Lc;                // 2*4096*4096
  unsigned short* Xlk  = att;                                        // alias (8.4MB)
  unsigned short* Qcat = att + (size_t)Bc * Lc * Lc;                 // 8192*32
  unsigned short* K1hi = Qcat + (size_t)Bc * Lc * 32;                // 8192*16
  unsigned short* K1lo = K1hi + (size_t)Bc * Lc * 16;
  unsigned short* K2hi = K1lo + (size_t)Bc * Lc * 16;
  unsigned short* K2lo = K2hi + (size_t)Bc * Lc * 16;
  unsigned short* Wcat = K2lo + (size_t)Bc * Lc * 16;                // 512*512

  init_wcat<<<dim3(64 + 1024), 256, 0, stream>>>(Mrow, wv, Wcat);
  qk_projpack<<<dim3(Lc / 32, Bc), 256, 0, stream>>>(x, wq, wk, Qcat, K1hi, K1lo, K2hi, K2lo);
  xT_pack<<<dim3(Lc / 64, 8, Bc), 256, 0, stream>>>(x, Xlk);
  v_gemm<<<dim3(512 / 128, Lc / 64, Bc), 256, 0, stream>>>(Wcat, Xlk, vbf);
  e_max<<<dim3(Lc / 64, 8, Bc), 256, 0, stream>>>(Qcat, K1hi, K2hi, Mrow);
  e_exp<<<dim3(Lc / 64, 8, Bc), 256, 0, stream>>>(Qcat, K1hi, K1lo, K2hi, K2lo, Mrow, att, Ssum);
  pv_gemm<<<dim3(256), 512, 3 * 16384 * sizeof(short), stream>>>(vbf, att, Ssum, x, gamma, out);
}

// Round 7
// 191.097 us; speedup vs baseline: 1.0928x; 1.0182x over previous
//
#include <hip/hip_runtime.h>
#include <cstdint>

// Shapes (fixed by the problem): B=2, C=64, G=4 -> CG=256, DQK=8, L=64*64=4096
constexpr int Bc  = 2;
constexpr int CGc = 256;
constexpr int Dc  = 8;
constexpr int Lc  = 4096;

typedef __attribute__((ext_vector_type(8))) short short8;
typedef __attribute__((ext_vector_type(4))) float floatx4;

__device__ inline unsigned short f2bf(float f) {
  union { float f; unsigned u; } v; v.f = f;
  unsigned r = v.u + 0x7fffu + ((v.u >> 16) & 1u);
  return (unsigned short)(r >> 16);
}
__device__ inline float bf2f(unsigned short h) {
  return __uint_as_float((unsigned)h << 16);
}

// ---------------------------------------------------------------------------
// Phase 0: Wcat[cc][k] bf16 = [[Wr, -Wi], [Wi, Wr]] (512x512) for v_gemm.
// ---------------------------------------------------------------------------
__global__ __launch_bounds__(256) void wcat_pack(const float* __restrict__ wv,
                                                 unsigned short* __restrict__ Wcat) {
  const int i  = blockIdx.x * 256 + threadIdx.x;  // 0..262143
  const int cc = i >> 9, k = i & 511;
  const int co = cc >> 8, c = cc & 255, ci = k >> 8, cin = k & 255;
  const float wr = wv[(size_t)c * CGc + cin];
  const float wi = wv[(size_t)(CGc + c) * CGc + cin];
  const float val = co == 0 ? (ci == 0 ? wr : -wi) : (ci == 0 ? wi : wr);
  Wcat[i] = f2bf(val);
}

// ---------------------------------------------------------------------------
// Phase 0b: LDS-transpose x -> Xlk[b][l][cin2] bf16 (cin2 = comp*256+cin).
// ---------------------------------------------------------------------------
__global__ __launch_bounds__(256) void xT_pack(const float* __restrict__ x,
                                               unsigned short* __restrict__ Xlk) {
  __shared__ float xs[64][65];
  const int tid = threadIdx.x;
  const int b   = blockIdx.z;
  const int l0  = blockIdx.x * 64;
  const int c0  = blockIdx.y * 64;
  const int lt  = tid & 63, r4 = tid >> 6;
#pragma unroll
  for (int p = 0; p < 16; ++p) {
    const int row  = p * 4 + r4;
    const int cin2 = c0 + row;
    const int comp = cin2 >> 8, cin = cin2 & 255;
    xs[row][lt] = x[((size_t)(comp * Bc + b) * CGc + cin) * Lc + l0 + lt];
  }
  __syncthreads();
#pragma unroll
  for (int p = 0; p < 16; ++p) {
    const int lr = p * 4 + r4;
    Xlk[((size_t)b * Lc + l0 + lr) * 512 + c0 + lt] = f2bf(xs[lt][lr]);
  }
}

// ---------------------------------------------------------------------------
// Phase 1 (fused): complex Q AND K projections + split-bf16 MFMA packing in
// one kernel (verified round-6 structure, unchanged).
// ---------------------------------------------------------------------------
__global__ __launch_bounds__(256) void qk_projpack(const float* __restrict__ x,
                                                   const float* __restrict__ wq,
                                                   const float* __restrict__ wk,
                                                   unsigned short* __restrict__ Qcat,
                                                   unsigned short* __restrict__ K1hi,
                                                   unsigned short* __restrict__ K1lo,
                                                   unsigned short* __restrict__ K2hi,
                                                   unsigned short* __restrict__ K2lo) {
  __shared__ float ws[4 * Dc * CGc];  // 32 KB: wq_r | wq_i | wk_r | wk_i
  __shared__ float qs[32][16];        // 2 KB: q~ rows
  __shared__ float ks[32][16];        // 2 KB: k~ rows
  const int tid = threadIdx.x;
  const int b   = blockIdx.y;
  for (int i = tid; i < 2 * Dc * CGc; i += 256) {
    ws[i]                 = wq[i];
    ws[2 * Dc * CGc + i]  = wk[i];
  }
  __syncthreads();
  const int d  = tid >> 5;   // 0..7
  const int ml = tid & 31;   // 0..31
  const int m  = blockIdx.x * 32 + ml;
  const float* xr = x + ((size_t)(0 * Bc + b) * CGc) * Lc + m;
  const float* xi = x + ((size_t)(1 * Bc + b) * CGc) * Lc + m;
  const float* wqr = ws + d * CGc;
  const float* wqi = ws + (Dc + d) * CGc;
  const float* wkr = ws + 2 * Dc * CGc + d * CGc;
  const float* wki = ws + 2 * Dc * CGc + (Dc + d) * CGc;
  float qer = 0.f, qei = 0.f, ker = 0.f, kei = 0.f;
#pragma unroll 4
  for (int cin = 0; cin < CGc; ++cin) {
    const float vr = xr[(size_t)cin * Lc];
    const float vi = xi[(size_t)cin * Lc];
    const float a1 = wqr[cin], b1 = wqi[cin];
    qer = fmaf(a1, vr, qer); qer = fmaf(-b1, vi, qer);
    qei = fmaf(a1, vi, qei); qei = fmaf(b1, vr, qei);
    const float a2 = wkr[cin], b2 = wki[cin];
    ker = fmaf(a2, vr, ker); ker = fmaf(-b2, vi, ker);
    kei = fmaf(a2, vi, kei); kei = fmaf(b2, vr, kei);
  }
  qs[ml][d] = qer;  qs[ml][8 + d] = qei;
  ks[ml][d] = ker;  ks[ml][8 + d] = kei;
  __syncthreads();
  // --- pack stage ---
  const int part = tid >> 5;       // 0..7
  const int rl   = tid & 31;       // local row
  const size_t r = (size_t)b * Lc + blockIdx.x * 32 + rl;
  if (part < 2) {
    unsigned u[8];
#pragma unroll
    for (int t = 0; t < 8; ++t) {
      const float v0 = qs[rl][2 * t], v1 = qs[rl][2 * t + 1];
      const unsigned short h0 = f2bf(v0), h1 = f2bf(v1);
      if (part == 0) {
        u[t] = (unsigned)h0 | ((unsigned)h1 << 16);
      } else {
        const unsigned short l0 = f2bf(v0 - bf2f(h0));
        const unsigned short l1 = f2bf(v1 - bf2f(h1));
        u[t] = (unsigned)l0 | ((unsigned)l1 << 16);
      }
    }
    uint4* dst = (uint4*)(Qcat + r * 32 + part * 16);
    dst[0] = make_uint4(u[0], u[1], u[2], u[3]);
    dst[1] = make_uint4(u[4], u[5], u[6], u[7]);
  } else if (part < 6) {
    float kv[16];
    if (part < 4) {
#pragma unroll
      for (int e = 0; e < 8; ++e) { kv[e] = ks[rl][e]; kv[8 + e] = -ks[rl][8 + e]; }
    } else {
#pragma unroll
      for (int e = 0; e < 8; ++e) { kv[e] = ks[rl][8 + e]; kv[8 + e] = ks[rl][e]; }
    }
    const int lo = part & 1;
    unsigned u[8];
#pragma unroll
    for (int t = 0; t < 8; ++t) {
      const unsigned short h0 = f2bf(kv[2 * t]), h1 = f2bf(kv[2 * t + 1]);
      if (!lo) {
        u[t] = (unsigned)h0 | ((unsigned)h1 << 16);
      } else {
        const unsigned short l0 = f2bf(kv[2 * t] - bf2f(h0));
        const unsigned short l1 = f2bf(kv[2 * t + 1] - bf2f(h1));
        u[t] = (unsigned)l0 | ((unsigned)l1 << 16);
      }
    }
    unsigned short* base = part < 4 ? (lo ? K1lo : K1hi) : (lo ? K2lo : K2hi);
    uint4* dst = (uint4*)(base + r * 16);
    dst[0] = make_uint4(u[0], u[1], u[2], u[3]);
    dst[1] = make_uint4(u[4], u[5], u[6], u[7]);
  }
}

// ---------------------------------------------------------------------------
// Phase 2: V projection as bf16 MFMA GEMM (unchanged, verified).
// ---------------------------------------------------------------------------
__global__ __launch_bounds__(256) void v_gemm(const unsigned short* __restrict__ Wcat,
                                              const unsigned short* __restrict__ Xlk,
                                              unsigned short* __restrict__ vbf) {
  __shared__ short As[128 * 64];
  __shared__ short Bs[64 * 64];
  const int tid  = threadIdx.x;
  const int b    = blockIdx.z;
  const int cc0  = blockIdx.x * 128;
  const int l0   = blockIdx.y * 64;
  const int wid  = tid >> 6, lane = tid & 63;
  const int wcc  = (wid >> 1) * 64;
  const int wl   = (wid & 1) * 32;
  const int lrow = lane & 15, quad = lane >> 4;
  floatx4 acc[4][2] = {};
  const unsigned short* wsrc = Wcat + (size_t)cc0 * 512;
  const unsigned short* xsrc = Xlk + ((size_t)b * Lc + l0) * 512;
  int s_off[4], g_off[4];
#pragma unroll
  for (int r = 0; r < 4; ++r) {
    const int idx = r * 256 + tid;
    const int row = idx >> 3, ch = idx & 7;
    s_off[r] = row * 64 + (ch ^ (row & 7)) * 8;
    g_off[r] = row * 512 + ch * 8;
  }
  short8 ar[4], br[2];
#pragma unroll
  for (int r = 0; r < 4; ++r) ar[r] = *(const short8*)(wsrc + g_off[r]);
#pragma unroll
  for (int r = 0; r < 2; ++r) br[r] = *(const short8*)(xsrc + g_off[r]);
  for (int k0 = 0; k0 < 512; k0 += 64) {
    __syncthreads();
#pragma unroll
    for (int r = 0; r < 4; ++r) *(short8*)&As[s_off[r]] = ar[r];
#pragma unroll
    for (int r = 0; r < 2; ++r) *(short8*)&Bs[s_off[r]] = br[r];
    __syncthreads();
    if (k0 + 64 < 512) {
#pragma unroll
      for (int r = 0; r < 4; ++r) ar[r] = *(const short8*)(wsrc + g_off[r] + k0 + 64);
#pragma unroll
      for (int r = 0; r < 2; ++r) br[r] = *(const short8*)(xsrc + g_off[r] + k0 + 64);
    }
#pragma unroll
    for (int kk = 0; kk < 64; kk += 32) {
      const int cb = kk >> 3;  // 0 or 4
      short8 af[4], bf[2];
#pragma unroll
      for (int i = 0; i < 4; ++i)
        af[i] = *(const short8*)&As[(wcc + i * 16 + lrow) * 64 +
                                    ((cb + quad) ^ (lrow & 7)) * 8];
#pragma unroll
      for (int j = 0; j < 2; ++j)
        bf[j] = *(const short8*)&Bs[(wl + j * 16 + lrow) * 64 +
                                    ((cb + quad) ^ (lrow & 7)) * 8];
#pragma unroll
      for (int i = 0; i < 4; ++i)
#pragma unroll
        for (int j = 0; j < 2; ++j)
          acc[i][j] = __builtin_amdgcn_mfma_f32_16x16x32_bf16(af[i], bf[j], acc[i][j], 0, 0, 0);
    }
  }
#pragma unroll
  for (int i = 0; i < 4; ++i) {
    const int ccb = cc0 + wcc + i * 16 + quad * 4;
#pragma unroll
    for (int j = 0; j < 2; ++j) {
      const int l = l0 + wl + j * 16 + lrow;
#pragma unroll
      for (int rg = 0; rg < 4; ++rg)
        vbf[((size_t)b * 512 + ccb + rg) * Lc + l] = f2bf(acc[i][j][rg]);
    }
  }
}

// ---------------------------------------------------------------------------
// Phase 3+4 fused: emax_exp. 1024 threads = 16 waves: 2 row-groups x 8
// l-slices of 512. Pass 1 (hi-only QK^T) -> per-wave row max -> LDS
// atomicMax combine (replaces global Mrow + init + atomics). Pass 2 (full
// split-bf16 QK^T) -> att = bf16(exp(E-M)), row sums -> LDS atomicAdd ->
// direct Ssum store (no global atomics, no init). Per-wave math identical
// to the verified e_max / e_exp kernels.
// ---------------------------------------------------------------------------
__global__ __launch_bounds__(1024) void emax_exp(const unsigned short* __restrict__ Qcat,
                                                 const unsigned short* __restrict__ K1hi,
                                                 const unsigned short* __restrict__ K1lo,
                                                 const unsigned short* __restrict__ K2hi,
                                                 const unsigned short* __restrict__ K2lo,
                                                 unsigned short* __restrict__ att,
                                                 float* __restrict__ Ssum) {
  __shared__ unsigned maxb[32];
  __shared__ float    sumb[32];
  const int tid  = threadIdx.x;
  const int wv   = tid >> 6, lane = tid & 63;
  const int lrow = lane & 15, quad = lane >> 4, qsel = quad & 1;
  const int b    = blockIdx.y;
  const int rg   = wv & 1;            // row-group (16 rows each)
  const int sl   = wv >> 1;           // l-slice 0..7
  const int m16  = blockIdx.x * 32 + rg * 16;
  const int lbeg = sl * 512;
  const size_t kb = (size_t)b * Lc;
  if (tid < 32) { maxb[tid] = 0u; sumb[tid] = 0.f; }
  __syncthreads();
  const short8 afrag = *(const short8*)(Qcat + (kb + m16 + lrow) * 32 + quad * 8);
  // ---- pass 1: hi-only row max over this wave's l-slice ----
  float mx[4] = {0.f, 0.f, 0.f, 0.f};
  for (int l0 = lbeg; l0 < lbeg + 512; l0 += 16) {
    const size_t l = kb + l0 + lrow;
    const short8 b1h = *(const short8*)(K1hi + l * 16 + qsel * 8);
    const short8 b2h = *(const short8*)(K2hi + l * 16 + qsel * 8);
    const floatx4 er = __builtin_amdgcn_mfma_f32_16x16x32_bf16(afrag, b1h, (floatx4){0.f, 0.f, 0.f, 0.f}, 0, 0, 0);
    const floatx4 ei = __builtin_amdgcn_mfma_f32_16x16x32_bf16(afrag, b2h, (floatx4){0.f, 0.f, 0.f, 0.f}, 0, 0, 0);
#pragma unroll
    for (int r = 0; r < 4; ++r) {
      float e = er[r] * er[r];
      e = fmaf(ei[r], ei[r], e);
      mx[r] = fmaxf(mx[r], e);
    }
  }
#pragma unroll
  for (int r = 0; r < 4; ++r) {
    float v = mx[r];
#pragma unroll
    for (int off = 1; off < 16; off <<= 1) v = fmaxf(v, __shfl_xor(v, off));
    if (lrow == 0)
      atomicMax(&maxb[rg * 16 + quad * 4 + r], __float_as_uint(v));  // E >= 0
  }
  __syncthreads();
  float Mv[4], sum[4] = {};
#pragma unroll
  for (int r = 0; r < 4; ++r) Mv[r] = __uint_as_float(maxb[rg * 16 + quad * 4 + r]);
  // ---- pass 2: refined E, exp, att store, row sums ----
  for (int l0 = lbeg; l0 < lbeg + 512; l0 += 16) {
    const size_t l = kb + l0 + lrow;
    const short8 b1h = *(const short8*)(K1hi + l * 16 + qsel * 8);
    const short8 b1l = *(const short8*)(K1lo + l * 16 + qsel * 8);
    const short8 b2h = *(const short8*)(K2hi + l * 16 + qsel * 8);
    const short8 b2l = *(const short8*)(K2lo + l * 16 + qsel * 8);
    floatx4 er = __builtin_amdgcn_mfma_f32_16x16x32_bf16(afrag, b1l, (floatx4){0.f, 0.f, 0.f, 0.f}, 0, 0, 0);
    er = __builtin_amdgcn_mfma_f32_16x16x32_bf16(afrag, b1h, er, 0, 0, 0);
    floatx4 ei = __builtin_amdgcn_mfma_f32_16x16x32_bf16(afrag, b2l, (floatx4){0.f, 0.f, 0.f, 0.f}, 0, 0, 0);
    ei = __builtin_amdgcn_mfma_f32_16x16x32_bf16(afrag, b2h, ei, 0, 0, 0);
#pragma unroll
    for (int r = 0; r < 4; ++r) {
      float e = er[r] * er[r];
      e = fmaf(ei[r], ei[r], e);
      const float wgt = __expf(e - Mv[r]);
      sum[r] += wgt;
      att[(kb + m16 + quad * 4 + r) * Lc + l0 + lrow] = f2bf(wgt);
    }
  }
#pragma unroll
  for (int r = 0; r < 4; ++r) {
    float v = sum[r];
#pragma unroll
    for (int off = 1; off < 16; off <<= 1) v += __shfl_xor(v, off);
    if (lrow == 0) atomicAdd(&sumb[rg * 16 + quad * 4 + r], v);
  }
  __syncthreads();
  if (tid < 32) Ssum[kb + blockIdx.x * 32 + tid] = sumb[tid];
}

// ---------------------------------------------------------------------------
// Phase 5: PV GEMM v3 — 1024 threads (16 waves = 4 waves/SIMD), 4-way
// split-K, K=128 tiles, 2 x 64 KB DMA-staged buffers, ONE barrier/phase:
//   phase p: vmcnt(0) [tile p issued a full phase ago -> cheap drain] ->
//   s_barrier [tile p complete; all waves done computing p-1] -> issue DMA
//   tile p+1 into buf (p+1)&1 (its readers finished before the barrier) ->
//   compute tile p. 32 phases.
//   K-partition: group g = wid>>2 owns chunks 4g..4g+3 (K [32g,32g+32)) of
//   each tile; quad indexes the k-subchunk exactly as in the verified
//   kernel; XOR swizzle (row&7 == lrow&7) unchanged -> same bank behavior.
//   Reduction: g0+=g1, g2+=g3 (128 KB LDS), then g0+=g2; group-0 epilogue
//   out = (gamma/Ssum[m])*acc + x. XCD-aware bijective block swizzle.
// ---------------------------------------------------------------------------
__device__ __forceinline__ void pv_stage128(const unsigned short* __restrict__ vsrc,
                                            const unsigned short* __restrict__ asrc,
                                            short* lds_buf, int k0, int wid, int lane) {
  const int rsub = lane >> 4;          // 0..3: row within 4-row block
  const int cs   = lane & 15;          // LDS chunk position within 256B row
#pragma unroll
  for (int t = 0; t < 4; ++t) {
    const int q    = wid * 4 + t;      // block id 0..63 (1 KB each)
    const int tile = q >> 5;           // 0 = A(v), 1 = B(att)
    const int j    = q & 31;           // 4-row group within tile
    const int row  = j * 4 + rsub;
    const int gch  = cs ^ (row & 7);   // inverse-swizzled global k-chunk
    const unsigned short* g =
        (tile == 0 ? vsrc : asrc) + (size_t)row * Lc + k0 + gch * 8;
    short* l = lds_buf + tile * 16384 + j * 512;  // wave-uniform dest base
    __builtin_amdgcn_global_load_lds(
        (const __attribute__((address_space(1))) void*)g,
        (__attribute__((address_space(3))) void*)l, 16, 0, 0);
  }
}

__device__ __forceinline__ void pv_compute128(const short* __restrict__ As,
                                              const short* __restrict__ Bs,
                                              int cb, int wcc, int wm, int lrow, int quad,
                                              floatx4 (&acc)[4][4]) {
  short8 af[4], bf[4];
#pragma unroll
  for (int i = 0; i < 4; ++i)
    af[i] = *(const short8*)&As[(wcc + i * 16 + lrow) * 128 +
                                ((cb + quad) ^ (lrow & 7)) * 8];
#pragma unroll
  for (int j = 0; j < 4; ++j)
    bf[j] = *(const short8*)&Bs[(wm + j * 16 + lrow) * 128 +
                                ((cb + quad) ^ (lrow & 7)) * 8];
#pragma unroll
  for (int i = 0; i < 4; ++i)
#pragma unroll
    for (int j = 0; j < 4; ++j)
      acc[i][j] = __builtin_amdgcn_mfma_f32_16x16x32_bf16(af[i], bf[j], acc[i][j], 0, 0, 0);
}

__global__ __launch_bounds__(1024, 1) void pv_gemm(const unsigned short* __restrict__ v,
                                                   const unsigned short* __restrict__ att,
                                                   const float* __restrict__ Ssum,
                                                   const float* __restrict__ x,
                                                   const float* __restrict__ gamma,
                                                   float* __restrict__ out) {
  // 128 KB dynamic: 2 buffers x {A 128x128 | B 128x128} bf16, XOR-swizzled.
  extern __shared__ short smem[];
  // XCD-aware bijective swizzle: 256 blocks, XCD k gets contiguous work ids.
  const int flat = blockIdx.x;
  const int swz  = (flat & 7) * 32 + (flat >> 3);
  const int b    = swz >> 7;
  const int rem  = swz & 127;
  const int m0   = (rem >> 2) * 128;   // 32 m-panels
  const int cc0  = (rem & 3) * 128;    // 4 cc-panels
  const int tid  = threadIdx.x;
  const int wid  = tid >> 6, lane = tid & 63;
  const int g    = wid >> 2;           // split-K group 0..3
  const int w4   = wid & 3;
  const int wcc  = (w4 >> 1) * 64;
  const int wm   = (w4 & 1) * 64;
  const int lrow = lane & 15, quad = lane >> 4;
  const int cb   = g * 4;              // k-chunk base (of 16 chunks)
  floatx4 acc[4][4] = {};
  const unsigned short* vsrc = v   + ((size_t)b * 512 + cc0) * Lc;
  const unsigned short* asrc = att + ((size_t)b * Lc + m0) * Lc;
  // Prologue: DMA tile 0 into buf0.
  pv_stage128(vsrc, asrc, smem, 0, wid, lane);
  for (int p = 0; p < 32; ++p) {
    asm volatile("s_waitcnt vmcnt(0)" ::: "memory");
    __builtin_amdgcn_s_barrier();       // tile p complete; p-1 compute done
    __builtin_amdgcn_sched_barrier(0);
    if (p + 1 < 32)
      pv_stage128(vsrc, asrc, smem + ((p + 1) & 1) * 32768, (p + 1) * 128, wid, lane);
    __builtin_amdgcn_sched_barrier(0);
    pv_compute128(smem + (p & 1) * 32768, smem + (p & 1) * 32768 + 16384,
                  cb, wcc, wm, lrow, quad, acc);
    __builtin_amdgcn_sched_barrier(0);
  }
  __syncthreads();  // all computes done before smem reuse for reduction
  float* red = (float*)smem;  // 32768 floats = 128 KB
  // Round 1: g1 -> red[0..16383], g3 -> red[16384..32767]
  if (g == 1 || g == 3) {
    float* dst = red + (g == 3 ? 16384 : 0);
#pragma unroll
    for (int i = 0; i < 4; ++i)
#pragma unroll
      for (int j = 0; j < 4; ++j) {
        const int tq = i * 4 + j;
        *(floatx4*)&dst[((w4 * 64 + lane) * 16 + (tq ^ (lane & 15))) * 4] = acc[i][j];
      }
  }
  __syncthreads();
  if (g == 0 || g == 2) {
    const float* src = red + (g == 2 ? 16384 : 0);
#pragma unroll
    for (int i = 0; i < 4; ++i)
#pragma unroll
      for (int j = 0; j < 4; ++j) {
        const int tq = i * 4 + j;
        const floatx4 o = *(const floatx4*)&src[((w4 * 64 + lane) * 16 + (tq ^ (lane & 15))) * 4];
        acc[i][j] += o;
      }
  }
  __syncthreads();
  // Round 2: g2 -> red[0..16383]
  if (g == 2) {
#pragma unroll
    for (int i = 0; i < 4; ++i)
#pragma unroll
      for (int j = 0; j < 4; ++j) {
        const int tq = i * 4 + j;
        *(floatx4*)&red[((w4 * 64 + lane) * 16 + (tq ^ (lane & 15))) * 4] = acc[i][j];
      }
  }
  __syncthreads();
  if (g == 0) {
#pragma unroll
    for (int i = 0; i < 4; ++i)
#pragma unroll
      for (int j = 0; j < 4; ++j) {
        const int tq = i * 4 + j;
        const floatx4 o = *(const floatx4*)&red[((w4 * 64 + lane) * 16 + (tq ^ (lane & 15))) * 4];
        acc[i][j] += o;
      }
    const float gm = gamma[0];
    float svj[4];
#pragma unroll
    for (int j = 0; j < 4; ++j)
      svj[j] = gm / Ssum[(size_t)b * Lc + m0 + wm + j * 16 + lrow];
#pragma unroll
    for (int i = 0; i < 4; ++i) {
      const int ccb = cc0 + wcc + i * 16 + quad * 4;
#pragma unroll
      for (int j = 0; j < 4; ++j) {
        const int m = m0 + wm + j * 16 + lrow;
#pragma unroll
        for (int rg = 0; rg < 4; ++rg) {
          const int cc   = ccb + rg;
          const int comp = cc >> 8, c = cc & 255;
          const size_t idx = (((size_t)comp * Bc + b) * CGc + c) * Lc + m;
          out[idx] = svj[j] * acc[i][j][rg] + x[idx];
        }
      }
    }
  }
}

// ---------------------------------------------------------------------------
extern "C" void kernel_launch(void* const* d_in, const int* in_sizes, int n_in,
                              void* d_out, int out_size, void* d_ws, size_t ws_size,
                              hipStream_t stream) {
  const float* x     = (const float*)d_in[0];
  const float* wq    = (const float*)d_in[1];
  const float* wk    = (const float*)d_in[2];
  const float* wv    = (const float*)d_in[3];
  const float* gamma = (const float*)d_in[4];
  float* out = (float*)d_out;

  // Workspace (~78.7 MB). Xlk aliases att (stream-ordered: v_gemm reads Xlk
  // before emax_exp overwrites the region with att). q/kk/Mrow slots
  // retained for layout stability (unused). Ssum needs no init (direct
  // store from emax_exp).
  float* q    = (float*)d_ws;                         // 131072 (unused)
  float* kk   = q    + (size_t)Bc * Lc * 16;          // 131072 (unused)
  float* Mrow = kk   + (size_t)Bc * Lc * 16;          // 8192 (unused)
  float* Ssum = Mrow + (size_t)Bc * Lc;               // 8192
  unsigned short* vbf  = (unsigned short*)(Ssum + (size_t)Bc * Lc);  // 2*512*4096
  unsigned short* att  = vbf + (size_t)Bc * 512 * Lc;                // 2*4096*4096
  unsigned short* Xlk  = att;                                        // alias (8.4MB)
  unsigned short* Qcat = att + (size_t)Bc * Lc * Lc;                 // 8192*32
  unsigned short* K1hi = Qcat + (size_t)Bc * Lc * 32;                // 8192*16
  unsigned short* K1lo = K1hi + (size_t)Bc * Lc * 16;
  unsigned short* K2hi = K1lo + (size_t)Bc * Lc * 16;
  unsigned short* K2lo = K2hi + (size_t)Bc * Lc * 16;
  unsigned short* Wcat = K2lo + (size_t)Bc * Lc * 16;                // 512*512

  wcat_pack<<<dim3((512 * 512) / 256), 256, 0, stream>>>(wv, Wcat);
  qk_projpack<<<dim3(Lc / 32, Bc), 256, 0, stream>>>(x, wq, wk, Qcat, K1hi, K1lo, K2hi, K2lo);
  xT_pack<<<dim3(Lc / 64, 8, Bc), 256, 0, stream>>>(x, Xlk);
  v_gemm<<<dim3(512 / 128, Lc / 64, Bc), 256, 0, stream>>>(Wcat, Xlk, vbf);
  emax_exp<<<dim3(Lc / 32, Bc), 1024, 0, stream>>>(Qcat, K1hi, K1lo, K2hi, K2lo, att, Ssum);
  pv_gemm<<<dim3(256), 1024, 2 * 32768 * sizeof(short), stream>>>(vbf, att, Ssum, x, gamma, out);
}